// Round 5
// baseline (289.297 us; speedup 1.0000x reference)
//
#include <hip/hip_runtime.h>
#include <hip/hip_bf16.h>

// MultiHeadAttention  B=2, S=2048, D=1024, H=16, Dh=64  (fp32 I/O)
// Round 17:
//  - attn_fused: BARRIER-FREE main loop. r12/r15/r16 all sit at ~46.5us with
//    MfmaUtil+VALUBusy ~= 73-77% regardless of schedule or LDS traffic ->
//    the invariant cost is the per-tile __syncthreads (vmcnt(0) drain +
//    wave convoy). K/V now load DIRECTLY to registers: the LDS XOR-swizzle
//    composed with GLDS linear write cancels (content = G[row][quad*8..],
//    G[row][32+quad*8..]), so per-wave global_load_dwordx4 fetches the
//    identical elements the LDS path delivered -> numerics unchanged.
//    No LDS, no barriers until the final merge. Waves free-run; compiler
//    emits counted per-wave vmcnt for register loads. In-wave 1-deep
//    prefetch: K(t+1) reloaded right after QK(t) (hidden under exp+PV),
//    V(t+1) after PV(t) (hidden under QK+exp). 32 queries/wave geometry
//    (VGPR ~180 < 256 cap; spill = the one catastrophic failure).
//  - gemm bodies unchanged (r8-verified BK=32).

#define SEQ     2048
#define DMODEL  1024
#define NHEADS  16
#define DH      64
#define MROWS   4096
#define M1      (1024*1024)
#define M4      (4*1024*1024)
#define SCQ     0.18033688f      // log2(e)/sqrt(64)

typedef __hip_bfloat16 bf16;
typedef __attribute__((ext_vector_type(8))) short  short8;  // 8 bf16 = 4 VGPR
typedef __attribute__((ext_vector_type(4))) float  f32x4;   // MFMA C/D

__device__ __forceinline__ bf16 f2b(float x) { return __float2bfloat16(x); }
__device__ __forceinline__ f32x4 mfma16(short8 a, short8 b, f32x4 c) {
    return __builtin_amdgcn_mfma_f32_16x16x32_bf16(a, b, c, 0, 0, 0);
}
__device__ __forceinline__ unsigned pk2(float a, float b) {
    union { __hip_bfloat162 h; unsigned u; } x;
    x.h = __float22bfloat162_rn(float2{a, b});
    return x.u;
}
__device__ __forceinline__ short8 pk8(float4 a, float4 b) {
    union { short8 s; unsigned u[4]; } x;
    x.u[0] = pk2(a.x, a.y); x.u[1] = pk2(a.z, a.w);
    x.u[2] = pk2(b.x, b.y); x.u[3] = pk2(b.z, b.w);
    return x.s;
}
__device__ __forceinline__ float fexp2(float x) {
    return __builtin_amdgcn_exp2f(x);     // raw v_exp_f32
}
#define GLDS(g, l) __builtin_amdgcn_global_load_lds( \
    (const __attribute__((address_space(1))) void*)(g), \
    (__attribute__((address_space(3))) void*)(l), 16, 0, 0)

// ---------------------------------------------------------------------------
// fp32 -> bf16 conversion kernels
// ---------------------------------------------------------------------------
__global__ __launch_bounds__(256) void cvt_all(
    const float* __restrict__ Wq, const float* __restrict__ Wk,
    const float* __restrict__ Wv, const float* __restrict__ Wo,
    const float* __restrict__ Q,  const float* __restrict__ K,
    const float* __restrict__ V,  bf16* __restrict__ dst)
{
    const size_t gid = (size_t)blockIdx.x * 256 + threadIdx.x;   // 2M threads
    const size_t e0 = gid * 8;
    const float* s;
    if (e0 < (size_t)4 * M1) {
        const float* w[4] = {Wq, Wk, Wv, Wo};
        s = w[e0 >> 20] + (e0 & (M1 - 1));
    } else {
        const float* a[4] = {nullptr, Q, K, V};
        s = a[e0 >> 22] + (e0 & (M4 - 1));
    }
    float4 x = *(const float4*)s, y = *(const float4*)(s + 4);
    *(short8*)((short*)dst + e0) = pk8(x, y);
}

__global__ __launch_bounds__(256) void cvt_w(
    const float* __restrict__ W0, const float* __restrict__ W1,
    const float* __restrict__ W2, const float* __restrict__ W3,
    bf16* __restrict__ dst)
{
    const int gid = blockIdx.x * 256 + threadIdx.x;
    const int t   = gid >> 17;
    const int off = (gid & 131071) * 8;
    const float* srcs[4] = {W0, W1, W2, W3};
    const float* s = srcs[t] + off;
    float4 a = *(const float4*)s, b = *(const float4*)(s + 4);
    *(short8*)((short*)dst + (size_t)gid * 8) = pk8(a, b);
}

__global__ __launch_bounds__(256) void cvt_1(
    const float* __restrict__ X, bf16* __restrict__ D)
{
    const int gid = blockIdx.x * 256 + threadIdx.x;
    const int off = gid * 8;
    float4 a = *(const float4*)(X + off), b = *(const float4*)(X + off + 4);
    *(short8*)((short*)D + off) = pk8(a, b);
}

// ---------------------------------------------------------------------------
// bf16 MFMA GEMM body (r8-verified, BK=32 single-buffer, 2 barriers/step).
// mode: 0 fp32 flat; 1 bf16 heads [B,H,S,DH]; 2 bf16 heads-T [B,H,DH,S] with
// key-permutation tau within 32-groups (inverse realized by attn PV reads).
// ---------------------------------------------------------------------------
template <int BN>
__device__ __forceinline__ void gemm_body(
    const bf16* __restrict__ A, const bf16* __restrict__ B,
    const float* __restrict__ bias, void* __restrict__ outp,
    int m0, int n0, int mode, int bias_m, float scale)
{
    __shared__ short As[128 * 32];
    __shared__ short Bs[BN * 32];
    constexpr int NI = BN / 32;

    const int tid  = threadIdx.x;
    const int lane = tid & 63;
    const int wv   = tid >> 6;
    const int wm   = (wv >> 1) * 64;
    const int wn   = (wv & 1) * (BN / 2);
    const int fn   = lane & 15;
    const int fq   = lane >> 4;

    const int srow = lane >> 2;
    const int scol = (lane & 3) * 8;

    const short* Ag = (const short*)A;
    const short* Bg = (const short*)B;

    f32x4 acc[4][NI];
#pragma unroll
    for (int i = 0; i < 4; ++i)
#pragma unroll
        for (int j = 0; j < NI; ++j) acc[i][j] = (f32x4){0.f, 0.f, 0.f, 0.f};

    for (int k0 = 0; k0 < DMODEL; k0 += 32) {
#pragma unroll
        for (int i = 0; i < 2; ++i) {
            const int rr = wv * 32 + i * 16;
            const short* ga = Ag + (size_t)(m0 + rr + srow) * DMODEL + k0 + scol;
            GLDS(ga, As + rr * 32);
        }
#pragma unroll
        for (int i = 0; i < BN / 64; ++i) {
            const int rr = wv * (BN / 4) + i * 16;
            const short* gb = Bg + (size_t)(n0 + rr + srow) * DMODEL + k0 + scol;
            GLDS(gb, Bs + rr * 32);
        }
        __syncthreads();

        short8 af[4], bfr[NI];
#pragma unroll
        for (int im = 0; im < 4; ++im)
            af[im] = *(const short8*)(As + (wm + im * 16 + fn) * 32 + fq * 8);
#pragma unroll
        for (int in = 0; in < NI; ++in)
            bfr[in] = *(const short8*)(Bs + (wn + in * 16 + fn) * 32 + fq * 8);
#pragma unroll
        for (int im = 0; im < 4; ++im)
#pragma unroll
            for (int in = 0; in < NI; ++in)
                acc[im][in] = mfma16(af[im], bfr[in], acc[im][in]);
        __syncthreads();
    }

#pragma unroll
    for (int im = 0; im < 4; ++im) {
#pragma unroll
        for (int in = 0; in < NI; ++in) {
#pragma unroll
            for (int r = 0; r < 4; ++r) {
                const int m = m0 + wm + im * 16 + fq * 4 + r;
                const int n = n0 + wn + in * 16 + fn;
                const float c = (acc[im][in][r] + (bias_m ? bias[m] : bias[n])) * scale;
                if (mode == 0) {
                    ((float*)outp)[(size_t)m * DMODEL + n] = c;
                } else if (mode == 1) {
                    const int b = m >> 11, s = m & (SEQ - 1);
                    const int h = n >> 6,  d = n & (DH - 1);
                    ((bf16*)outp)[(((size_t)(b * NHEADS + h) * SEQ) + s) * DH + d] = f2b(c);
                } else {
                    const int h = m >> 6,  d = m & (DH - 1);
                    const int b = n >> 11, s = n & (SEQ - 1);
                    const int p = s & 31;
                    const int sp = (s & ~31) | ((p & 12) << 1) | ((p & 16) >> 2) | (p & 3);
                    ((bf16*)outp)[(((size_t)(b * NHEADS + h) * DH) + d) * SEQ + sp] = f2b(c);
                }
            }
        }
    }
}

__global__ __launch_bounds__(256, 3) void gemm_one(
    const bf16* A, const bf16* B, const float* bias, void* out,
    int mode, int bias_m, float scale)
{
    gemm_body<128>(A, B, bias, out, blockIdx.x * 128, blockIdx.y * 128,
                   mode, bias_m, scale);
}

__global__ __launch_bounds__(256, 3) void gemm_fin(
    const bf16* A, const bf16* B, const float* bias, void* out)
{
    gemm_body<64>(A, B, bias, out, blockIdx.x * 128, blockIdx.y * 64, 0, 0, 1.f);
}

__global__ __launch_bounds__(256, 3) void gemm_qkv(
    const bf16* Qb, const bf16* Kb, const bf16* Vb, const bf16* Wb,
    const float* bq, const float* bk, const float* bv,
    bf16* qp, bf16* kp, bf16* vp)
{
    const int blk = blockIdx.x;
    const int z = blk >> 8, t = blk & 255;
    if (z == 0)
        gemm_body<128>(Qb, Wb,          bq, qp, (t >> 3) * 128, (t & 7) * 128, 1, 0, SCQ);
    else if (z == 1)
        gemm_body<128>(Kb, Wb + M1,     bk, kp, (t >> 3) * 128, (t & 7) * 128, 1, 0, 1.f);
    else
        gemm_body<128>(Wb + 2 * M1, Vb, bv, vp, (t >> 5) * 128, (t & 31) * 128, 2, 1, 1.f);
}

// ---------------------------------------------------------------------------
// Fused split-K attention: 512 blocks x 512 threads (8 waves), NO main-loop
// LDS/barriers. Waves 0-3 (half 0): keys 0..1023; waves 4-7 (half 1): keys
// 1024..2047. Each wave: 32 queries, loads full K/V tiles direct to regs.
// Direct addresses (swizzle-cancelled, == LDS-path content):
//   kf0 = kh[(kbase+g*16+n)*64 + quad*8], kf1 = +32
//   vf0 = vh[(gd*16+n)*2048 + kbase + quad*8], vf1 = +32
// Per tile: QK(Kr) -> reload Kr(t+1) -> exp/pack -> lacc+PV(Vr) -> reload
// Vr(t+1). Compiler emits counted per-wave vmcnt; waves free-run.
// Merge via LDS scratch with 3 uniform end-barriers (unchanged from r15).
// q,k: [B,H,S,DH] bf16 (q pre-scaled by log2e/8); vt: [B,H,DH,S] bf16,
// key-permuted (tau). out: concat [B,S,DMODEL] bf16.
// ---------------------------------------------------------------------------
__global__ __launch_bounds__(512, 2) void attn_fused(
    const bf16* __restrict__ q,
    const bf16* __restrict__ k,
    const bf16* __restrict__ vt,
    bf16* __restrict__ out)
{
    __shared__ float SCR[256 * 34];      // 34.8 KB merge scratch only

    const int tid  = threadIdx.x;
    const int wave = tid >> 6;           // 0..7
    const int half = wave >> 2;          // key-half
    const int w4   = wave & 3;
    const int lane = tid & 63;
    const int n    = lane & 15;
    const int quad = lane >> 4;

    const int blk  = blockIdx.x;         // 0..511
    const int xcd  = blk & 7;
    const int rest = blk >> 3;           // 0..63
    const int qt   = rest & 15;
    const int bh   = ((rest >> 4) << 3) | xcd;
    const int q0w  = qt * 128 + w4 * 32;
    const int kt0  = half * 16;

    const short* qh = (const short*)(q  + (size_t)bh * SEQ * DH);
    const short* kh = (const short*)(k  + (size_t)bh * SEQ * DH);
    const short* vh = (const short*)(vt + (size_t)bh * DH * SEQ);

    short8 qf00, qf01, qf10, qf11;
    {
        const short* qr0 = qh + (size_t)(q0w + n) * DH;
        qf00 = *(const short8*)(qr0 + quad * 8);
        qf01 = *(const short8*)(qr0 + 32 + quad * 8);
        const short* qr1 = qh + (size_t)(q0w + 16 + n) * DH;
        qf10 = *(const short8*)(qr1 + quad * 8);
        qf11 = *(const short8*)(qr1 + 32 + quad * 8);
    }

    const short8 onesv = {(short)0x3F80, (short)0x3F80, (short)0x3F80, (short)0x3F80,
                          (short)0x3F80, (short)0x3F80, (short)0x3F80, (short)0x3F80};
    const f32x4 Zv = (f32x4){0.f, 0.f, 0.f, 0.f};

    f32x4 O[4][2];                       // [gd][qg]
#pragma unroll
    for (int gd = 0; gd < 4; ++gd)
#pragma unroll
        for (int qg = 0; qg < 2; ++qg) O[gd][qg] = Zv;
    f32x4 lc0 = Zv, lc1 = Zv;

    // direct-load pointers (element units); bumped per tile
    const short* kp[4];
    const short* vp[4];
#pragma unroll
    for (int g = 0; g < 4; ++g)
        kp[g] = kh + (size_t)(kt0 * 64 + g * 16 + n) * 64 + quad * 8;
#pragma unroll
    for (int gd = 0; gd < 4; ++gd)
        vp[gd] = vh + (size_t)(gd * 16 + n) * SEQ + kt0 * 64 + quad * 8;

    short8 Kr[4][2];                     // K-tile fragments (32 VGPR)
    short8 Vr[4][2];                     // V-tile fragments (32 VGPR)

    // prologue: tile 0
#pragma unroll
    for (int g = 0; g < 4; ++g) {
        Kr[g][0] = *(const short8*)(kp[g]);
        Kr[g][1] = *(const short8*)(kp[g] + 32);
    }
#pragma unroll
    for (int gd = 0; gd < 4; ++gd) {
        Vr[gd][0] = *(const short8*)(vp[gd]);
        Vr[gd][1] = *(const short8*)(vp[gd] + 32);
    }

#pragma unroll 1
    for (int t = 0; t < 16; ++t) {
        // ---- QK^T from Kr ----
        f32x4 st[4][2];
#pragma unroll
        for (int g = 0; g < 4; ++g) {
            f32x4 s0 = mfma16(Kr[g][0], qf00, Zv);
            st[g][0] = mfma16(Kr[g][1], qf01, s0);
            f32x4 s1 = mfma16(Kr[g][0], qf10, Zv);
            st[g][1] = mfma16(Kr[g][1], qf11, s1);
        }
        // ---- prefetch K(t+1) (Kr dead after QK) ----
        if (t < 15) {
#pragma unroll
            for (int g = 0; g < 4; ++g) {
                kp[g] += 64 * 64;
                Kr[g][0] = *(const short8*)(kp[g]);
                Kr[g][1] = *(const short8*)(kp[g] + 32);
            }
        }
        // ---- exp/pack -> P[2][2] ----
        short8 P[2][2];
#pragma unroll
        for (int tt = 0; tt < 2; ++tt) {
#pragma unroll
            for (int qg = 0; qg < 2; ++qg) {
                union { short8 s8; unsigned u[4]; } bb;
                bb.u[0] = pk2(fexp2(st[2*tt][qg][0]),   fexp2(st[2*tt][qg][1]));
                bb.u[1] = pk2(fexp2(st[2*tt][qg][2]),   fexp2(st[2*tt][qg][3]));
                bb.u[2] = pk2(fexp2(st[2*tt+1][qg][0]), fexp2(st[2*tt+1][qg][1]));
                bb.u[3] = pk2(fexp2(st[2*tt+1][qg][2]), fexp2(st[2*tt+1][qg][3]));
                P[tt][qg] = bb.s8;
            }
        }
        // ---- lacc + PV from Vr ----
        lc0 = mfma16(onesv, P[0][0], lc0);
        lc1 = mfma16(onesv, P[0][1], lc1);
        lc0 = mfma16(onesv, P[1][0], lc0);
        lc1 = mfma16(onesv, P[1][1], lc1);
#pragma unroll
        for (int gd = 0; gd < 4; ++gd) {
            O[gd][0] = mfma16(Vr[gd][0], P[0][0], O[gd][0]);
            O[gd][0] = mfma16(Vr[gd][1], P[1][0], O[gd][0]);
            O[gd][1] = mfma16(Vr[gd][0], P[0][1], O[gd][1]);
            O[gd][1] = mfma16(Vr[gd][1], P[1][1], O[gd][1]);
        }
        // ---- prefetch V(t+1) (Vr dead after PV) ----
        if (t < 15) {
#pragma unroll
            for (int gd = 0; gd < 4; ++gd) {
                vp[gd] += 64;
                Vr[gd][0] = *(const short8*)(vp[gd]);
                Vr[gd][1] = *(const short8*)(vp[gd] + 32);
            }
        }
    }

    // ---- intra-block split-K merge ----
    // scratch: per lane 34 floats (32 O + 2 l), stride 34 (2-way bank alias =
    // free; 8B aligned for b64). 256 lanes x 136B = 34 KB.
    float* scr = SCR + (size_t)(w4 * 64 + lane) * 34;
    const float l0 = lc0[0];
    const float l1 = lc1[0];

    __syncthreads();
    if (half == 1) {
#pragma unroll
        for (int gd = 0; gd < 4; ++gd)
#pragma unroll
            for (int qg = 0; qg < 2; ++qg) {
                *(float2*)(scr + (gd * 2 + qg) * 4)     = float2{O[gd][qg][0], O[gd][qg][1]};
                *(float2*)(scr + (gd * 2 + qg) * 4 + 2) = float2{O[gd][qg][2], O[gd][qg][3]};
            }
        *(float2*)(scr + 32) = float2{l0, l1};
    }
    __syncthreads();
    if (half == 0) {
        const float2 lo = *(const float2*)(scr + 32);
        const float inv0 = 1.0f / (l0 + lo.x);
        const float inv1 = 1.0f / (l1 + lo.y);
        const int b = bh >> 4;
        const int h = bh & (NHEADS - 1);
#pragma unroll
        for (int gd = 0; gd < 4; ++gd) {
#pragma unroll
            for (int qg = 0; qg < 2; ++qg) {
                const float iv = qg ? inv1 : inv0;
                float2 a = *(const float2*)(scr + (gd * 2 + qg) * 4);
                float2 c = *(const float2*)(scr + (gd * 2 + qg) * 4 + 2);
                const int s = q0w + qg * 16 + n;
                uint2 o;
                o.x = pk2((O[gd][qg][0] + a.x) * iv, (O[gd][qg][1] + a.y) * iv);
                o.y = pk2((O[gd][qg][2] + c.x) * iv, (O[gd][qg][3] + c.y) * iv);
                *(uint2*)(out + ((size_t)(b * SEQ + s)) * DMODEL + h * DH + gd * 16 + quad * 4) = o;
            }
        }
    }
}

// ---------------------------------------------------------------------------
// Single-kernel attention — fallback path only (r9-verified).
// ---------------------------------------------------------------------------
__global__ __launch_bounds__(256) void attn_mfma(
    const bf16* __restrict__ q,
    const bf16* __restrict__ k,
    const bf16* __restrict__ vt,
    bf16* __restrict__ out)
{
    __shared__ short Kt[2][64 * 64];
    __shared__ short Vt[2][64 * 64];

    const int tid  = threadIdx.x;
    const int wave = tid >> 6;
    const int lane = tid & 63;
    const int n    = lane & 15;
    const int quad = lane >> 4;

    const int blk  = blockIdx.x;
    const int xcd  = blk & 7;
    const int rest = blk >> 3;
    const int qt   = rest & 15;
    const int bh   = ((rest >> 4) << 3) | xcd;
    const int q0w  = qt * 128 + wave * 32;

    const bf16* qhead = q  + (size_t)bh * SEQ * DH;
    const bf16* khead = k  + (size_t)bh * SEQ * DH;
    const bf16* vhead = vt + (size_t)bh * DH * SEQ;

    short8 qf[2][2];
#pragma unroll
    for (int qg = 0; qg < 2; ++qg) {
        const short* qr = (const short*)(qhead + (size_t)(q0w + qg * 16 + n) * DH);
        qf[qg][0] = *(const short8*)(qr + quad * 8);
        qf[qg][1] = *(const short8*)(qr + 32 + quad * 8);
    }

    const short8 onesv = {(short)0x3F80, (short)0x3F80, (short)0x3F80, (short)0x3F80,
                          (short)0x3F80, (short)0x3F80, (short)0x3F80, (short)0x3F80};
    const f32x4 Zv = (f32x4){0.f, 0.f, 0.f, 0.f};

    f32x4 O[4][2];
#pragma unroll
    for (int gd = 0; gd < 4; ++gd)
#pragma unroll
        for (int qg = 0; qg < 2; ++qg) O[gd][qg] = Zv;
    f32x4 lacc[2] = {Zv, Zv};

    const int srow = lane >> 3;
    const int schk = (lane & 7) ^ srow;
    const int off0 = ((quad       ^ (n & 7)) * 8);
    const int off1 = (((4 + quad) ^ (n & 7)) * 8);

    auto stage = [&](int kt, int buf) {
        const int kbase = kt * 64;
#pragma unroll
        for (int i = 0; i < 2; ++i) {
            const int r = wave * 16 + i * 8 + srow;
            const char* gk = (const char*)(khead + (size_t)(kbase + r) * DH) + schk * 16;
            const char* gv = (const char*)(vhead + (size_t)r * SEQ + kbase) + schk * 16;
            GLDS(gk, Kt[buf] + (wave * 16 + i * 8) * 64);
            GLDS(gv, Vt[buf] + (wave * 16 + i * 8) * 64);
        }
    };

    auto tile_body = [&](const short* KtB, const short* VtB) {
        f32x4 st[4][2];
#pragma unroll
        for (int g = 0; g < 4; ++g) {
            const short* kr = KtB + (g * 16 + n) * 64;
            short8 kf0 = *(const short8*)(kr + off0);
            short8 kf1 = *(const short8*)(kr + off1);
#pragma unroll
            for (int qg = 0; qg < 2; ++qg) {
                f32x4 s = mfma16(kf0, qf[qg][0], Zv);
                s = mfma16(kf1, qf[qg][1], s);
                st[g][qg] = s;
            }
        }
        short8 bP[2][2];
#pragma unroll
        for (int t = 0; t < 2; ++t) {
#pragma unroll
            for (int qg = 0; qg < 2; ++qg) {
                union { short8 s8; unsigned u[4]; } bb;
                bb.u[0] = pk2(fexp2(st[2*t][qg][0]),   fexp2(st[2*t][qg][1]));
                bb.u[1] = pk2(fexp2(st[2*t][qg][2]),   fexp2(st[2*t][qg][3]));
                bb.u[2] = pk2(fexp2(st[2*t+1][qg][0]), fexp2(st[2*t+1][qg][1]));
                bb.u[3] = pk2(fexp2(st[2*t+1][qg][2]), fexp2(st[2*t+1][qg][3]));
                bP[t][qg] = bb.s8;
                lacc[qg] = mfma16(onesv, bP[t][qg], lacc[qg]);
            }
        }
#pragma unroll
        for (int gd = 0; gd < 4; ++gd) {
            const short* vr = VtB + (gd * 16 + n) * 64;
            short8 vf0 = *(const short8*)(vr + off0);
            short8 vf1 = *(const short8*)(vr + off1);
#pragma unroll
            for (int qg = 0; qg < 2; ++qg) {
                O[gd][qg] = mfma16(vf0, bP[0][qg], O[gd][qg]);
                O[gd][qg] = mfma16(vf1, bP[1][qg], O[gd][qg]);
            }
        }
    };

    stage(0, 0);
#pragma unroll 1
    for (int kt = 0; kt < SEQ / 64; kt += 2) {
        __syncthreads();
        stage(kt + 1, 1);
        tile_body(Kt[0], Vt[0]);
        __syncthreads();
        if (kt + 2 < SEQ / 64) stage(kt + 2, 0);
        tile_body(Kt[1], Vt[1]);
    }

    const float inv0 = 1.0f / lacc[0][0];
    const float inv1 = 1.0f / lacc[1][0];
    const int b = bh >> 4;
    const int h = bh & (NHEADS - 1);
#pragma unroll
    for (int gd = 0; gd < 4; ++gd) {
#pragma unroll
        for (int qg = 0; qg < 2; ++qg) {
            const float iv = qg ? inv1 : inv0;
            const int s = q0w + qg * 16 + n;
            uint2 o;
            o.x = pk2(O[gd][qg][0] * iv, O[gd][qg][1] * iv);
            o.y = pk2(O[gd][qg][2] * iv, O[gd][qg][3] * iv);
            *(uint2*)(out + ((size_t)(b * SEQ + s)) * DMODEL + h * DH + gd * 16 + quad * 4) = o;
        }
    }
}

// ---------------------------------------------------------------------------
extern "C" void kernel_launch(void* const* d_in, const int* in_sizes, int n_in,
                              void* d_out, int out_size, void* d_ws, size_t ws_size,
                              hipStream_t stream) {
    const float* Q  = (const float*)d_in[0];
    const float* K  = (const float*)d_in[1];
    const float* V  = (const float*)d_in[2];
    const float* Wq = (const float*)d_in[3];
    const float* Wk = (const float*)d_in[4];
    const float* Wv = (const float*)d_in[5];
    const float* Wo = (const float*)d_in[6];
    const float* bq = (const float*)d_in[7];
    const float* bk = (const float*)d_in[8];
    const float* bv = (const float*)d_in[9];
    const float* bo = (const float*)d_in[10];

    // kp/vp live in d_out (16MB) as scratch; final GEMM rewrites d_out fully.
    bf16* kp = (bf16*)d_out;
    bf16* vp = kp + M4;

    dim3 bb(256);
    dim3 gqk(MROWS / 128, DMODEL / 128);   // (32,8)
    dim3 gvv(DMODEL / 128, MROWS / 128);   // (8,32)
    dim3 gfin(MROWS / 128, DMODEL / 64);   // (32,16)

    if (ws_size >= (size_t)40 * 1024 * 1024) {
        // fused: Wb 8MB | Qb 8 | Kb 8 | Vb 8 | qp 8 = 40MB; ao aliases Qb.
        bf16* Wb = (bf16*)d_ws;
        bf16* Qb = Wb + 4 * M1;
        bf16* Kb = Qb + M4;
        bf16* Vb = Kb + M4;
        bf16* qp = Vb + M4;
        bf16* ao = Qb;

        cvt_all<<<8192, bb, 0, stream>>>(Wq, Wk, Wv, Wo, Q, K, V, Wb);
        gemm_qkv<<<768, bb, 0, stream>>>(Qb, Kb, Vb, Wb, bq, bk, bv, qp, kp, vp);
        attn_fused<<<512, 512, 0, stream>>>(qp, kp, vp, ao);
        gemm_fin<<<gfin, bb, 0, stream>>>(ao, Wb + 3 * M1, bo, d_out);
    } else {
        // sequential: Wb 8 + Xb 8 + qp 8 = 24MB; ao aliases Xb
        bf16* Wb = (bf16*)d_ws;
        bf16* Xb = Wb + 4 * M1;
        bf16* qp = Xb + M4;
        bf16* ao = Xb;

        cvt_w<<<2048, bb, 0, stream>>>(Wq, Wk, Wv, Wo, Wb);
        cvt_1<<<2048, bb, 0, stream>>>(Q, Xb);
        gemm_one<<<gqk, bb, 0, stream>>>(Xb, Wb, bq, qp, 1, 0, SCQ);
        cvt_1<<<2048, bb, 0, stream>>>(K, Xb);
        gemm_one<<<gqk, bb, 0, stream>>>(Xb, Wb + M1, bk, kp, 1, 0, 1.f);
        cvt_1<<<2048, bb, 0, stream>>>(V, Xb);
        gemm_one<<<gvv, bb, 0, stream>>>(Wb + 2 * M1, Xb, bv, vp, 2, 1, 1.f);
        attn_mfma<<<512, bb, 0, stream>>>(qp, kp, vp, ao);
        gemm_fin<<<gfin, bb, 0, stream>>>(ao, Wb + 3 * M1, bo, d_out);
    }
}

// Round 6
// 215.064 us; speedup vs baseline: 1.3452x; 1.3452x over previous
//
#include <hip/hip_runtime.h>
#include <hip/hip_bf16.h>

// MultiHeadAttention  B=2, S=2048, D=1024, H=16, Dh=64  (fp32 I/O)
// Round 18:
//  - attn_fused: r15 structure (best verified: attn 46.3us, total 209.88)
//    with two safe micro-opts:
//    (a) stage address hoisting: persistent per-wave byte pointers for the
//        4 GLDS ops, incremented by constants (K +8192B/tile, V +128B/tile)
//        instead of recomputed mul+add chains -> ~30-40 fewer VALU/period.
//    (b) s_setprio(1) around Y-phase MFMA cluster (T5): halves drift within
//        a period (no intra-period sync) -> scheduler has X(VALU)/Y(MFMA)
//        waves to arbitrate (m191 attn case, +4-7%).
//  - r17 (direct-to-reg, no LDS) reverted: compiler sank prefetches
//    (VGPR 88), latency-bound at 127us. LDS multicast + GLDS staging is
//    load-bearing.
//  - gemm bodies unchanged (r8-verified BK=32).

#define SEQ     2048
#define DMODEL  1024
#define NHEADS  16
#define DH      64
#define MROWS   4096
#define M1      (1024*1024)
#define M4      (4*1024*1024)
#define SCQ     0.18033688f      // log2(e)/sqrt(64)

typedef __hip_bfloat16 bf16;
typedef __attribute__((ext_vector_type(8))) short  short8;  // 8 bf16 = 4 VGPR
typedef __attribute__((ext_vector_type(4))) float  f32x4;   // MFMA C/D

__device__ __forceinline__ bf16 f2b(float x) { return __float2bfloat16(x); }
__device__ __forceinline__ f32x4 mfma16(short8 a, short8 b, f32x4 c) {
    return __builtin_amdgcn_mfma_f32_16x16x32_bf16(a, b, c, 0, 0, 0);
}
__device__ __forceinline__ unsigned pk2(float a, float b) {
    union { __hip_bfloat162 h; unsigned u; } x;
    x.h = __float22bfloat162_rn(float2{a, b});
    return x.u;
}
__device__ __forceinline__ short8 pk8(float4 a, float4 b) {
    union { short8 s; unsigned u[4]; } x;
    x.u[0] = pk2(a.x, a.y); x.u[1] = pk2(a.z, a.w);
    x.u[2] = pk2(b.x, b.y); x.u[3] = pk2(b.z, b.w);
    return x.s;
}
__device__ __forceinline__ float fexp2(float x) {
    return __builtin_amdgcn_exp2f(x);     // raw v_exp_f32
}
#define GLDS(g, l) __builtin_amdgcn_global_load_lds( \
    (const __attribute__((address_space(1))) void*)(g), \
    (__attribute__((address_space(3))) void*)(l), 16, 0, 0)

// ---------------------------------------------------------------------------
// fp32 -> bf16 conversion kernels
// ---------------------------------------------------------------------------
__global__ __launch_bounds__(256) void cvt_all(
    const float* __restrict__ Wq, const float* __restrict__ Wk,
    const float* __restrict__ Wv, const float* __restrict__ Wo,
    const float* __restrict__ Q,  const float* __restrict__ K,
    const float* __restrict__ V,  bf16* __restrict__ dst)
{
    const size_t gid = (size_t)blockIdx.x * 256 + threadIdx.x;   // 2M threads
    const size_t e0 = gid * 8;
    const float* s;
    if (e0 < (size_t)4 * M1) {
        const float* w[4] = {Wq, Wk, Wv, Wo};
        s = w[e0 >> 20] + (e0 & (M1 - 1));
    } else {
        const float* a[4] = {nullptr, Q, K, V};
        s = a[e0 >> 22] + (e0 & (M4 - 1));
    }
    float4 x = *(const float4*)s, y = *(const float4*)(s + 4);
    *(short8*)((short*)dst + e0) = pk8(x, y);
}

__global__ __launch_bounds__(256) void cvt_w(
    const float* __restrict__ W0, const float* __restrict__ W1,
    const float* __restrict__ W2, const float* __restrict__ W3,
    bf16* __restrict__ dst)
{
    const int gid = blockIdx.x * 256 + threadIdx.x;
    const int t   = gid >> 17;
    const int off = (gid & 131071) * 8;
    const float* srcs[4] = {W0, W1, W2, W3};
    const float* s = srcs[t] + off;
    float4 a = *(const float4*)s, b = *(const float4*)(s + 4);
    *(short8*)((short*)dst + (size_t)gid * 8) = pk8(a, b);
}

__global__ __launch_bounds__(256) void cvt_1(
    const float* __restrict__ X, bf16* __restrict__ D)
{
    const int gid = blockIdx.x * 256 + threadIdx.x;
    const int off = gid * 8;
    float4 a = *(const float4*)(X + off), b = *(const float4*)(X + off + 4);
    *(short8*)((short*)D + off) = pk8(a, b);
}

// ---------------------------------------------------------------------------
// bf16 MFMA GEMM body (r8-verified, BK=32 single-buffer, 2 barriers/step).
// mode: 0 fp32 flat; 1 bf16 heads [B,H,S,DH]; 2 bf16 heads-T [B,H,DH,S] with
// key-permutation tau within 32-groups (inverse realized by attn PV reads).
// ---------------------------------------------------------------------------
template <int BN>
__device__ __forceinline__ void gemm_body(
    const bf16* __restrict__ A, const bf16* __restrict__ B,
    const float* __restrict__ bias, void* __restrict__ outp,
    int m0, int n0, int mode, int bias_m, float scale)
{
    __shared__ short As[128 * 32];
    __shared__ short Bs[BN * 32];
    constexpr int NI = BN / 32;

    const int tid  = threadIdx.x;
    const int lane = tid & 63;
    const int wv   = tid >> 6;
    const int wm   = (wv >> 1) * 64;
    const int wn   = (wv & 1) * (BN / 2);
    const int fn   = lane & 15;
    const int fq   = lane >> 4;

    const int srow = lane >> 2;
    const int scol = (lane & 3) * 8;

    const short* Ag = (const short*)A;
    const short* Bg = (const short*)B;

    f32x4 acc[4][NI];
#pragma unroll
    for (int i = 0; i < 4; ++i)
#pragma unroll
        for (int j = 0; j < NI; ++j) acc[i][j] = (f32x4){0.f, 0.f, 0.f, 0.f};

    for (int k0 = 0; k0 < DMODEL; k0 += 32) {
#pragma unroll
        for (int i = 0; i < 2; ++i) {
            const int rr = wv * 32 + i * 16;
            const short* ga = Ag + (size_t)(m0 + rr + srow) * DMODEL + k0 + scol;
            GLDS(ga, As + rr * 32);
        }
#pragma unroll
        for (int i = 0; i < BN / 64; ++i) {
            const int rr = wv * (BN / 4) + i * 16;
            const short* gb = Bg + (size_t)(n0 + rr + srow) * DMODEL + k0 + scol;
            GLDS(gb, Bs + rr * 32);
        }
        __syncthreads();

        short8 af[4], bfr[NI];
#pragma unroll
        for (int im = 0; im < 4; ++im)
            af[im] = *(const short8*)(As + (wm + im * 16 + fn) * 32 + fq * 8);
#pragma unroll
        for (int in = 0; in < NI; ++in)
            bfr[in] = *(const short8*)(Bs + (wn + in * 16 + fn) * 32 + fq * 8);
#pragma unroll
        for (int im = 0; im < 4; ++im)
#pragma unroll
            for (int in = 0; in < NI; ++in)
                acc[im][in] = mfma16(af[im], bfr[in], acc[im][in]);
        __syncthreads();
    }

#pragma unroll
    for (int im = 0; im < 4; ++im) {
#pragma unroll
        for (int in = 0; in < NI; ++in) {
#pragma unroll
            for (int r = 0; r < 4; ++r) {
                const int m = m0 + wm + im * 16 + fq * 4 + r;
                const int n = n0 + wn + in * 16 + fn;
                const float c = (acc[im][in][r] + (bias_m ? bias[m] : bias[n])) * scale;
                if (mode == 0) {
                    ((float*)outp)[(size_t)m * DMODEL + n] = c;
                } else if (mode == 1) {
                    const int b = m >> 11, s = m & (SEQ - 1);
                    const int h = n >> 6,  d = n & (DH - 1);
                    ((bf16*)outp)[(((size_t)(b * NHEADS + h) * SEQ) + s) * DH + d] = f2b(c);
                } else {
                    const int h = m >> 6,  d = m & (DH - 1);
                    const int b = n >> 11, s = n & (SEQ - 1);
                    const int p = s & 31;
                    const int sp = (s & ~31) | ((p & 12) << 1) | ((p & 16) >> 2) | (p & 3);
                    ((bf16*)outp)[(((size_t)(b * NHEADS + h) * DH) + d) * SEQ + sp] = f2b(c);
                }
            }
        }
    }
}

__global__ __launch_bounds__(256, 3) void gemm_one(
    const bf16* A, const bf16* B, const float* bias, void* out,
    int mode, int bias_m, float scale)
{
    gemm_body<128>(A, B, bias, out, blockIdx.x * 128, blockIdx.y * 128,
                   mode, bias_m, scale);
}

__global__ __launch_bounds__(256, 3) void gemm_fin(
    const bf16* A, const bf16* B, const float* bias, void* out)
{
    gemm_body<64>(A, B, bias, out, blockIdx.x * 128, blockIdx.y * 64, 0, 0, 1.f);
}

__global__ __launch_bounds__(256, 3) void gemm_qkv(
    const bf16* Qb, const bf16* Kb, const bf16* Vb, const bf16* Wb,
    const float* bq, const float* bk, const float* bv,
    bf16* qp, bf16* kp, bf16* vp)
{
    const int blk = blockIdx.x;
    const int z = blk >> 8, t = blk & 255;
    if (z == 0)
        gemm_body<128>(Qb, Wb,          bq, qp, (t >> 3) * 128, (t & 7) * 128, 1, 0, SCQ);
    else if (z == 1)
        gemm_body<128>(Kb, Wb + M1,     bk, kp, (t >> 3) * 128, (t & 7) * 128, 1, 0, 1.f);
    else
        gemm_body<128>(Wb + 2 * M1, Vb, bv, vp, (t >> 5) * 128, (t & 31) * 128, 2, 1, 1.f);
}

// ---------------------------------------------------------------------------
// Fused split-K attention: 512 blocks x 512 threads (8 waves).
// Waves 0-3 (half 0): keys 0..1023; waves 4-7 (half 1): keys 1024..2047.
// Each half has private K/V double-buffers (64 KB LDS total, 2 blocks/CU).
// r15 in-wave 1-deep pipeline, straight-line macro form (17 barriers):
//   period 0 : stage_K(1), stage_V(0), X(0)->PA
//   period t : stage_K(t+1), stage_V(t), X(t)->cur, Y(t-1) from prev
//   period 16: Y(15)
// R18: stage pointers hoisted (K +8192B/tile, V +128B/tile); setprio(1)
// around Y's MFMA cluster.
// q,k: [B,H,S,DH] bf16 (q pre-scaled by log2e/8); vt: [B,H,DH,S] bf16,
// key-permuted (tau). out: concat [B,S,DMODEL] bf16.
// ---------------------------------------------------------------------------

// QK^T for key-group G (16 keys), both q-groups: S0 (qg=0), S1 (qg=1)
#define QKG(KTB, G, S0, S1) { \
    const short* kr_ = (KTB) + ((G) * 16 + n) * 64; \
    short8 kf0_ = *(const short8*)(kr_ + off0); \
    short8 kf1_ = *(const short8*)(kr_ + off1); \
    S0 = mfma16(kf0_, qf00, Zv); S0 = mfma16(kf1_, qf01, S0); \
    S1 = mfma16(kf0_, qf10, Zv); S1 = mfma16(kf1_, qf11, S1); }

// pack exp(SA)|exp(SB) (two adjacent key-groups) into one bf16x8
#define PKP(SA, SB, DST) { \
    union { short8 s8; unsigned u[4]; } bb_; \
    bb_.u[0] = pk2(fexp2(SA[0]), fexp2(SA[1])); \
    bb_.u[1] = pk2(fexp2(SA[2]), fexp2(SA[3])); \
    bb_.u[2] = pk2(fexp2(SB[0]), fexp2(SB[1])); \
    bb_.u[3] = pk2(fexp2(SB[2]), fexp2(SB[3])); \
    DST = bb_.s8; }

// X phase: QK^T + exp/pack for tile T -> P(tt,qg) = P00,P01,P10,P11
#define XPH(T, P00, P01, P10, P11) { \
    const short* KtB_ = Kb0 + ((T) & 1) * 4096; \
    f32x4 sa0_, sa1_, sb0_, sb1_; \
    QKG(KtB_, 0, sa0_, sa1_) \
    QKG(KtB_, 1, sb0_, sb1_) \
    PKP(sa0_, sb0_, P00) \
    PKP(sa1_, sb1_, P01) \
    QKG(KtB_, 2, sa0_, sa1_) \
    QKG(KtB_, 3, sb0_, sb1_) \
    PKP(sa0_, sb0_, P10) \
    PKP(sa1_, sb1_, P11) }

// PV for output d-group GD
#define PVG(VTB, GD, P00, P01, P10, P11) { \
    const short* vr_ = (VTB) + ((GD) * 16 + n) * 64; \
    short8 vf0_ = *(const short8*)(vr_ + off0); \
    short8 vf1_ = *(const short8*)(vr_ + off1); \
    O[GD][0] = mfma16(vf0_, P00, O[GD][0]); \
    O[GD][0] = mfma16(vf1_, P10, O[GD][0]); \
    O[GD][1] = mfma16(vf0_, P01, O[GD][1]); \
    O[GD][1] = mfma16(vf1_, P11, O[GD][1]); }

// Y phase: lacc + PV for tile T from P-tile (setprio-wrapped MFMA cluster)
#define YPH(T, P00, P01, P10, P11) { \
    const short* VtB_ = Vb0 + ((T) & 1) * 4096; \
    __builtin_amdgcn_s_setprio(1); \
    lc0 = mfma16(onesv, P00, lc0); \
    lc1 = mfma16(onesv, P01, lc1); \
    lc0 = mfma16(onesv, P10, lc0); \
    lc1 = mfma16(onesv, P11, lc1); \
    PVG(VtB_, 0, P00, P01, P10, P11) \
    PVG(VtB_, 1, P00, P01, P10, P11) \
    PVG(VtB_, 2, P00, P01, P10, P11) \
    PVG(VtB_, 3, P00, P01, P10, P11) \
    __builtin_amdgcn_s_setprio(0); }

__global__ __launch_bounds__(512, 4) void attn_fused(
    const bf16* __restrict__ q,
    const bf16* __restrict__ k,
    const bf16* __restrict__ vt,
    bf16* __restrict__ out)
{
    __shared__ short LB[32768];      // 64 KB: [half][{K0,K1,V0,V1} x 4096 shorts]

    const int tid  = threadIdx.x;
    const int wave = tid >> 6;           // 0..7
    const int half = wave >> 2;          // key-half
    const int w4   = wave & 3;
    const int lane = tid & 63;
    const int n    = lane & 15;
    const int quad = lane >> 4;

    const int blk  = blockIdx.x;         // 0..511
    const int xcd  = blk & 7;
    const int rest = blk >> 3;           // 0..63
    const int qt   = rest & 15;
    const int bh   = ((rest >> 4) << 3) | xcd;
    const int q0w  = qt * 128 + w4 * 32;
    const int kt0  = half * 16;

    const bf16* qhead = q  + (size_t)bh * SEQ * DH;
    const bf16* khead = k  + (size_t)bh * SEQ * DH;
    const bf16* vhead = vt + (size_t)bh * DH * SEQ;

    short* Kb0 = LB + half * 16384;              // [buf][4096]
    short* Vb0 = LB + half * 16384 + 8192;       // [buf][4096]

    short8 qf00, qf01, qf10, qf11;
    {
        const short* qr0 = (const short*)(qhead + (size_t)(q0w + n) * DH);
        qf00 = *(const short8*)(qr0 + quad * 8);
        qf01 = *(const short8*)(qr0 + 32 + quad * 8);
        const short* qr1 = (const short*)(qhead + (size_t)(q0w + 16 + n) * DH);
        qf10 = *(const short8*)(qr1 + quad * 8);
        qf11 = *(const short8*)(qr1 + 32 + quad * 8);
    }

    const short8 onesv = {(short)0x3F80, (short)0x3F80, (short)0x3F80, (short)0x3F80,
                          (short)0x3F80, (short)0x3F80, (short)0x3F80, (short)0x3F80};
    const f32x4 Zv = (f32x4){0.f, 0.f, 0.f, 0.f};

    f32x4 O[4][2];
#pragma unroll
    for (int gd = 0; gd < 4; ++gd)
#pragma unroll
        for (int qg = 0; qg < 2; ++qg) O[gd][qg] = Zv;
    f32x4 lc0 = Zv, lc1 = Zv;            // single l-chain per qg

    const int srow = lane >> 3;
    const int schk = (lane & 7) ^ srow;
    const int off0 = ((quad       ^ (n & 7)) * 8);
    const int off1 = (((4 + quad) ^ (n & 7)) * 8);

    // hoisted stage pointers (bytes). Derivation vs r15:
    //   gk(kt,i) = khead_b + (kt*64 + w4*16 + i*8 + srow)*128 + schk*16
    //   gv(kt,i) = vhead_b + (w4*16 + i*8 + srow)*4096 + kt*128 + schk*16
    // steps: K +8192B per tile, V +128B per tile; i=1 offsets +1024B / +32768B.
    const char* gk0 = (const char*)khead +
        (size_t)(kt0 * 64 + w4 * 16 + srow) * 128 + schk * 16;
    const char* gv0 = (const char*)vhead +
        (size_t)(w4 * 16 + srow) * 4096 + kt0 * 128 + schk * 16;
    short* const ldsK = Kb0 + (w4 * 16) * 64;
    short* const ldsV = Vb0 + (w4 * 16) * 64;

    auto stageK = [&](int buf) {
        GLDS(gk0,        ldsK + buf * 4096);
        GLDS(gk0 + 1024, ldsK + buf * 4096 + 512);
        gk0 += 8192;
    };
    auto stageV = [&](int buf) {
        GLDS(gv0,         ldsV + buf * 4096);
        GLDS(gv0 + 32768, ldsV + buf * 4096 + 512);
        gv0 += 128;
    };

    short8 PA00, PA01, PA10, PA11;
    short8 PB00, PB01, PB10, PB11;

    stageK(0);                            // prologue: K(0) -> buf0

    // period 0
    __syncthreads();
    stageK(1);                            // K(1) -> buf1
    stageV(0);                            // V(0) -> buf0
    XPH(0, PA00, PA01, PA10, PA11)

#pragma unroll 1
    for (int t = 1; t < 15; t += 2) {
        // period t (odd): cur=PB, prev=PA
        __syncthreads();
        stageK((t + 1) & 1);              // K(t+1)
        stageV(t & 1);                    // V(t)
        XPH(t, PB00, PB01, PB10, PB11)
        YPH(t - 1, PA00, PA01, PA10, PA11)
        // period t+1 (even): cur=PA, prev=PB
        __syncthreads();
        stageK((t + 2) & 1);              // K(t+2)
        stageV((t + 1) & 1);              // V(t+1)
        XPH(t + 1, PA00, PA01, PA10, PA11)
        YPH(t, PB00, PB01, PB10, PB11)
    }
    // period 15: cur=PB, prev=PA (no more K to stage)
    __syncthreads();
    stageV(1);                            // V(15)
    XPH(15, PB00, PB01, PB10, PB11)
    YPH(14, PA00, PA01, PA10, PA11)
    // period 16: drain
    __syncthreads();
    YPH(15, PB00, PB01, PB10, PB11)

    // ---- intra-block split-K merge ----
    // scratch: per lane 34 floats (32 O + 2 l), stride 34 (2-way bank alias =
    // free; 8B aligned for b64). 256 lanes x 136B = 34 KB < 64 KB.
    float* scr = (float*)LB + (size_t)(w4 * 64 + lane) * 34;
    const float l0 = lc0[0];
    const float l1 = lc1[0];

    __syncthreads();                     // all tile reads done; LB reusable
    if (half == 1) {
#pragma unroll
        for (int gd = 0; gd < 4; ++gd)
#pragma unroll
            for (int qg = 0; qg < 2; ++qg) {
                *(float2*)(scr + (gd * 2 + qg) * 4)     = float2{O[gd][qg][0], O[gd][qg][1]};
                *(float2*)(scr + (gd * 2 + qg) * 4 + 2) = float2{O[gd][qg][2], O[gd][qg][3]};
            }
        *(float2*)(scr + 32) = float2{l0, l1};
    }
    __syncthreads();
    if (half == 0) {
        const float2 lo = *(const float2*)(scr + 32);
        const float inv0 = 1.0f / (l0 + lo.x);
        const float inv1 = 1.0f / (l1 + lo.y);
        const int b = bh >> 4;
        const int h = bh & (NHEADS - 1);
#pragma unroll
        for (int gd = 0; gd < 4; ++gd) {
#pragma unroll
            for (int qg = 0; qg < 2; ++qg) {
                const float iv = qg ? inv1 : inv0;
                float2 a = *(const float2*)(scr + (gd * 2 + qg) * 4);
                float2 c = *(const float2*)(scr + (gd * 2 + qg) * 4 + 2);
                const int s = q0w + qg * 16 + n;
                uint2 o;
                o.x = pk2((O[gd][qg][0] + a.x) * iv, (O[gd][qg][1] + a.y) * iv);
                o.y = pk2((O[gd][qg][2] + c.x) * iv, (O[gd][qg][3] + c.y) * iv);
                *(uint2*)(out + ((size_t)(b * SEQ + s)) * DMODEL + h * DH + gd * 16 + quad * 4) = o;
            }
        }
    }
}

#undef QKG
#undef PKP
#undef XPH
#undef PVG
#undef YPH

// ---------------------------------------------------------------------------
// Single-kernel attention — fallback path only (r9-verified).
// ---------------------------------------------------------------------------
__global__ __launch_bounds__(256) void attn_mfma(
    const bf16* __restrict__ q,
    const bf16* __restrict__ k,
    const bf16* __restrict__ vt,
    bf16* __restrict__ out)
{
    __shared__ short Kt[2][64 * 64];
    __shared__ short Vt[2][64 * 64];

    const int tid  = threadIdx.x;
    const int wave = tid >> 6;
    const int lane = tid & 63;
    const int n    = lane & 15;
    const int quad = lane >> 4;

    const int blk  = blockIdx.x;
    const int xcd  = blk & 7;
    const int rest = blk >> 3;
    const int qt   = rest & 15;
    const int bh   = ((rest >> 4) << 3) | xcd;
    const int q0w  = qt * 128 + wave * 32;

    const bf16* qhead = q  + (size_t)bh * SEQ * DH;
    const bf16* khead = k  + (size_t)bh * SEQ * DH;
    const bf16* vhead = vt + (size_t)bh * DH * SEQ;

    short8 qf[2][2];
#pragma unroll
    for (int qg = 0; qg < 2; ++qg) {
        const short* qr = (const short*)(qhead + (size_t)(q0w + qg * 16 + n) * DH);
        qf[qg][0] = *(const short8*)(qr + quad * 8);
        qf[qg][1] = *(const short8*)(qr + 32 + quad * 8);
    }

    const short8 onesv = {(short)0x3F80, (short)0x3F80, (short)0x3F80, (short)0x3F80,
                          (short)0x3F80, (short)0x3F80, (short)0x3F80, (short)0x3F80};
    const f32x4 Zv = (f32x4){0.f, 0.f, 0.f, 0.f};

    f32x4 O[4][2];
#pragma unroll
    for (int gd = 0; gd < 4; ++gd)
#pragma unroll
        for (int qg = 0; qg < 2; ++qg) O[gd][qg] = Zv;
    f32x4 lacc[2] = {Zv, Zv};

    const int srow = lane >> 3;
    const int schk = (lane & 7) ^ srow;
    const int off0 = ((quad       ^ (n & 7)) * 8);
    const int off1 = (((4 + quad) ^ (n & 7)) * 8);

    auto stage = [&](int kt, int buf) {
        const int kbase = kt * 64;
#pragma unroll
        for (int i = 0; i < 2; ++i) {
            const int r = wave * 16 + i * 8 + srow;
            const char* gk = (const char*)(khead + (size_t)(kbase + r) * DH) + schk * 16;
            const char* gv = (const char*)(vhead + (size_t)r * SEQ + kbase) + schk * 16;
            GLDS(gk, Kt[buf] + (wave * 16 + i * 8) * 64);
            GLDS(gv, Vt[buf] + (wave * 16 + i * 8) * 64);
        }
    };

    auto tile_body = [&](const short* KtB, const short* VtB) {
        f32x4 st[4][2];
#pragma unroll
        for (int g = 0; g < 4; ++g) {
            const short* kr = KtB + (g * 16 + n) * 64;
            short8 kf0 = *(const short8*)(kr + off0);
            short8 kf1 = *(const short8*)(kr + off1);
#pragma unroll
            for (int qg = 0; qg < 2; ++qg) {
                f32x4 s = mfma16(kf0, qf[qg][0], Zv);
                s = mfma16(kf1, qf[qg][1], s);
                st[g][qg] = s;
            }
        }
        short8 bP[2][2];
#pragma unroll
        for (int t = 0; t < 2; ++t) {
#pragma unroll
            for (int qg = 0; qg < 2; ++qg) {
                union { short8 s8; unsigned u[4]; } bb;
                bb.u[0] = pk2(fexp2(st[2*t][qg][0]),   fexp2(st[2*t][qg][1]));
                bb.u[1] = pk2(fexp2(st[2*t][qg][2]),   fexp2(st[2*t][qg][3]));
                bb.u[2] = pk2(fexp2(st[2*t+1][qg][0]), fexp2(st[2*t+1][qg][1]));
                bb.u[3] = pk2(fexp2(st[2*t+1][qg][2]), fexp2(st[2*t+1][qg][3]));
                bP[t][qg] = bb.s8;
                lacc[qg] = mfma16(onesv, bP[t][qg], lacc[qg]);
            }
        }
#pragma unroll
        for (int gd = 0; gd < 4; ++gd) {
            const short* vr = VtB + (gd * 16 + n) * 64;
            short8 vf0 = *(const short8*)(vr + off0);
            short8 vf1 = *(const short8*)(vr + off1);
#pragma unroll
            for (int qg = 0; qg < 2; ++qg) {
                O[gd][qg] = mfma16(vf0, bP[0][qg], O[gd][qg]);
                O[gd][qg] = mfma16(vf1, bP[1][qg], O[gd][qg]);
            }
        }
    };

    stage(0, 0);
#pragma unroll 1
    for (int kt = 0; kt < SEQ / 64; kt += 2) {
        __syncthreads();
        stage(kt + 1, 1);
        tile_body(Kt[0], Vt[0]);
        __syncthreads();
        if (kt + 2 < SEQ / 64) stage(kt + 2, 0);
        tile_body(Kt[1], Vt[1]);
    }

    const float inv0 = 1.0f / lacc[0][0];
    const float inv1 = 1.0f / lacc[1][0];
    const int b = bh >> 4;
    const int h = bh & (NHEADS - 1);
#pragma unroll
    for (int gd = 0; gd < 4; ++gd) {
#pragma unroll
        for (int qg = 0; qg < 2; ++qg) {
            const float iv = qg ? inv1 : inv0;
            const int s = q0w + qg * 16 + n;
            uint2 o;
            o.x = pk2(O[gd][qg][0] * iv, O[gd][qg][1] * iv);
            o.y = pk2(O[gd][qg][2] * iv, O[gd][qg][3] * iv);
            *(uint2*)(out + ((size_t)(b * SEQ + s)) * DMODEL + h * DH + gd * 16 + quad * 4) = o;
        }
    }
}

// ---------------------------------------------------------------------------
extern "C" void kernel_launch(void* const* d_in, const int* in_sizes, int n_in,
                              void* d_out, int out_size, void* d_ws, size_t ws_size,
                              hipStream_t stream) {
    const float* Q  = (const float*)d_in[0];
    const float* K  = (const float*)d_in[1];
    const float* V  = (const float*)d_in[2];
    const float* Wq = (const float*)d_in[3];
    const float* Wk = (const float*)d_in[4];
    const float* Wv = (const float*)d_in[5];
    const float* Wo = (const float*)d_in[6];
    const float* bq = (const float*)d_in[7];
    const float* bk = (const float*)d_in[8];
    const float* bv = (const float*)d_in[9];
    const float* bo = (const float*)d_in[10];

    // kp/vp live in d_out (16MB) as scratch; final GEMM rewrites d_out fully.
    bf16* kp = (bf16*)d_out;
    bf16* vp = kp + M4;

    dim3 bb(256);
    dim3 gqk(MROWS / 128, DMODEL / 128);   // (32,8)
    dim3 gvv(DMODEL / 128, MROWS / 128);   // (8,32)
    dim3 gfin(MROWS / 128, DMODEL / 64);   // (32,16)

    if (ws_size >= (size_t)40 * 1024 * 1024) {
        // fused: Wb 8MB | Qb 8 | Kb 8 | Vb 8 | qp 8 = 40MB; ao aliases Qb.
        bf16* Wb = (bf16*)d_ws;
        bf16* Qb = Wb + 4 * M1;
        bf16* Kb = Qb + M4;
        bf16* Vb = Kb + M4;
        bf16* qp = Vb + M4;
        bf16* ao = Qb;

        cvt_all<<<8192, bb, 0, stream>>>(Wq, Wk, Wv, Wo, Q, K, V, Wb);
        gemm_qkv<<<768, bb, 0, stream>>>(Qb, Kb, Vb, Wb, bq, bk, bv, qp, kp, vp);
        attn_fused<<<512, 512, 0, stream>>>(qp, kp, vp, ao);
        gemm_fin<<<gfin, bb, 0, stream>>>(ao, Wb + 3 * M1, bo, d_out);
    } else {
        // sequential: Wb 8 + Xb 8 + qp 8 = 24MB; ao aliases Xb
        bf16* Wb = (bf16*)d_ws;
        bf16* Xb = Wb + 4 * M1;
        bf16* qp = Xb + M4;
        bf16* ao = Xb;

        cvt_w<<<2048, bb, 0, stream>>>(Wq, Wk, Wv, Wo, Wb);
        cvt_1<<<2048, bb, 0, stream>>>(Q, Xb);
        gemm_one<<<gqk, bb, 0, stream>>>(Xb, Wb, bq, qp, 1, 0, SCQ);
        cvt_1<<<2048, bb, 0, stream>>>(K, Xb);
        gemm_one<<<gqk, bb, 0, stream>>>(Xb, Wb + M1, bk, kp, 1, 0, 1.f);
        cvt_1<<<2048, bb, 0, stream>>>(V, Xb);
        gemm_one<<<gvv, bb, 0, stream>>>(Wb + 2 * M1, Xb, bv, vp, 2, 1, 1.f);
        attn_mfma<<<512, bb, 0, stream>>>(qp, kp, vp, ao);
        gemm_fin<<<gfin, bb, 0, stream>>>(ao, Wb + 3 * M1, bo, d_out);
    }
}

// Round 7
// 211.409 us; speedup vs baseline: 1.3684x; 1.0173x over previous
//
#include <hip/hip_runtime.h>
#include <hip/hip_bf16.h>

// MultiHeadAttention  B=2, S=2048, D=1024, H=16, Dh=64  (fp32 I/O)
// Round 19:
//  - GEMM path (the ~2/3 of total time that never shows in top-5):
//    (a) gemm_body: T3-min double-buffered staging. stage(t+1) issued BEFORE
//        compute(t) into the other LDS buffer -> load latency hides under
//        MFMA+ds_read; second barrier per K-step eliminated (33 vs 64
//        barriers). Hazards audited: reads of buf p drained by preceding
//        barrier; writes to buf p^1 target a buffer whose readers finished
//        one barrier earlier. LDS 16->32KB, still 3 blocks/CU.
//    (b) gemm_fin: BN=64 -> BN=128 tiles (grid (32,8)). BN=64 had half the
//        MFMA-per-barrier density (tile ladder: 64-wide ~2x slower).
//  - attn_fused: r18 verified (45.0us: hoisted stage pointers + setprio).
//  - totals are +-5us noisy; per-dispatch counters are the signal.

#define SEQ     2048
#define DMODEL  1024
#define NHEADS  16
#define DH      64
#define MROWS   4096
#define M1      (1024*1024)
#define M4      (4*1024*1024)
#define SCQ     0.18033688f      // log2(e)/sqrt(64)

typedef __hip_bfloat16 bf16;
typedef __attribute__((ext_vector_type(8))) short  short8;  // 8 bf16 = 4 VGPR
typedef __attribute__((ext_vector_type(4))) float  f32x4;   // MFMA C/D

__device__ __forceinline__ bf16 f2b(float x) { return __float2bfloat16(x); }
__device__ __forceinline__ f32x4 mfma16(short8 a, short8 b, f32x4 c) {
    return __builtin_amdgcn_mfma_f32_16x16x32_bf16(a, b, c, 0, 0, 0);
}
__device__ __forceinline__ unsigned pk2(float a, float b) {
    union { __hip_bfloat162 h; unsigned u; } x;
    x.h = __float22bfloat162_rn(float2{a, b});
    return x.u;
}
__device__ __forceinline__ short8 pk8(float4 a, float4 b) {
    union { short8 s; unsigned u[4]; } x;
    x.u[0] = pk2(a.x, a.y); x.u[1] = pk2(a.z, a.w);
    x.u[2] = pk2(b.x, b.y); x.u[3] = pk2(b.z, b.w);
    return x.s;
}
__device__ __forceinline__ float fexp2(float x) {
    return __builtin_amdgcn_exp2f(x);     // raw v_exp_f32
}
#define GLDS(g, l) __builtin_amdgcn_global_load_lds( \
    (const __attribute__((address_space(1))) void*)(g), \
    (__attribute__((address_space(3))) void*)(l), 16, 0, 0)

// ---------------------------------------------------------------------------
// fp32 -> bf16 conversion kernels
// ---------------------------------------------------------------------------
__global__ __launch_bounds__(256) void cvt_all(
    const float* __restrict__ Wq, const float* __restrict__ Wk,
    const float* __restrict__ Wv, const float* __restrict__ Wo,
    const float* __restrict__ Q,  const float* __restrict__ K,
    const float* __restrict__ V,  bf16* __restrict__ dst)
{
    const size_t gid = (size_t)blockIdx.x * 256 + threadIdx.x;   // 2M threads
    const size_t e0 = gid * 8;
    const float* s;
    if (e0 < (size_t)4 * M1) {
        const float* w[4] = {Wq, Wk, Wv, Wo};
        s = w[e0 >> 20] + (e0 & (M1 - 1));
    } else {
        const float* a[4] = {nullptr, Q, K, V};
        s = a[e0 >> 22] + (e0 & (M4 - 1));
    }
    float4 x = *(const float4*)s, y = *(const float4*)(s + 4);
    *(short8*)((short*)dst + e0) = pk8(x, y);
}

__global__ __launch_bounds__(256) void cvt_w(
    const float* __restrict__ W0, const float* __restrict__ W1,
    const float* __restrict__ W2, const float* __restrict__ W3,
    bf16* __restrict__ dst)
{
    const int gid = blockIdx.x * 256 + threadIdx.x;
    const int t   = gid >> 17;
    const int off = (gid & 131071) * 8;
    const float* srcs[4] = {W0, W1, W2, W3};
    const float* s = srcs[t] + off;
    float4 a = *(const float4*)s, b = *(const float4*)(s + 4);
    *(short8*)((short*)dst + (size_t)gid * 8) = pk8(a, b);
}

__global__ __launch_bounds__(256) void cvt_1(
    const float* __restrict__ X, bf16* __restrict__ D)
{
    const int gid = blockIdx.x * 256 + threadIdx.x;
    const int off = gid * 8;
    float4 a = *(const float4*)(X + off), b = *(const float4*)(X + off + 4);
    *(short8*)((short*)D + off) = pk8(a, b);
}

// ---------------------------------------------------------------------------
// bf16 MFMA GEMM body. R19: T3-min double-buffered staging (1 barrier/step).
// mode: 0 fp32 flat; 1 bf16 heads [B,H,S,DH]; 2 bf16 heads-T [B,H,DH,S] with
// key-permutation tau within 32-groups (inverse realized by attn PV reads).
// ---------------------------------------------------------------------------
template <int BN>
__device__ __forceinline__ void gemm_body(
    const bf16* __restrict__ A, const bf16* __restrict__ B,
    const float* __restrict__ bias, void* __restrict__ outp,
    int m0, int n0, int mode, int bias_m, float scale)
{
    __shared__ short As[2][128 * 32];
    __shared__ short Bs[2][BN * 32];
    constexpr int NI = BN / 32;
    constexpr int NSTEP = DMODEL / 32;

    const int tid  = threadIdx.x;
    const int lane = tid & 63;
    const int wv   = tid >> 6;
    const int wm   = (wv >> 1) * 64;
    const int wn   = (wv & 1) * (BN / 2);
    const int fn   = lane & 15;
    const int fq   = lane >> 4;

    const int srow = lane >> 2;
    const int scol = (lane & 3) * 8;

    const short* Ag = (const short*)A;
    const short* Bg = (const short*)B;

    f32x4 acc[4][NI];
#pragma unroll
    for (int i = 0; i < 4; ++i)
#pragma unroll
        for (int j = 0; j < NI; ++j) acc[i][j] = (f32x4){0.f, 0.f, 0.f, 0.f};

    auto stage = [&](int k0, int buf) {
#pragma unroll
        for (int i = 0; i < 2; ++i) {
            const int rr = wv * 32 + i * 16;
            const short* ga = Ag + (size_t)(m0 + rr + srow) * DMODEL + k0 + scol;
            GLDS(ga, As[buf] + rr * 32);
        }
#pragma unroll
        for (int i = 0; i < BN / 64; ++i) {
            const int rr = wv * (BN / 4) + i * 16;
            const short* gb = Bg + (size_t)(n0 + rr + srow) * DMODEL + k0 + scol;
            GLDS(gb, Bs[buf] + rr * 32);
        }
    };

    stage(0, 0);
    __syncthreads();

#pragma unroll 2
    for (int step = 0; step < NSTEP; ++step) {
        if (step + 1 < NSTEP) stage((step + 1) * 32, (step + 1) & 1);

        const short* Asb = As[step & 1];
        const short* Bsb = Bs[step & 1];
        short8 af[4], bfr[NI];
#pragma unroll
        for (int im = 0; im < 4; ++im)
            af[im] = *(const short8*)(Asb + (wm + im * 16 + fn) * 32 + fq * 8);
#pragma unroll
        for (int in = 0; in < NI; ++in)
            bfr[in] = *(const short8*)(Bsb + (wn + in * 16 + fn) * 32 + fq * 8);
#pragma unroll
        for (int im = 0; im < 4; ++im)
#pragma unroll
            for (int in = 0; in < NI; ++in)
                acc[im][in] = mfma16(af[im], bfr[in], acc[im][in]);

        __syncthreads();   // drains stage(step+1) writes + this buf's reads
    }

#pragma unroll
    for (int im = 0; im < 4; ++im) {
#pragma unroll
        for (int in = 0; in < NI; ++in) {
#pragma unroll
            for (int r = 0; r < 4; ++r) {
                const int m = m0 + wm + im * 16 + fq * 4 + r;
                const int n = n0 + wn + in * 16 + fn;
                const float c = (acc[im][in][r] + (bias_m ? bias[m] : bias[n])) * scale;
                if (mode == 0) {
                    ((float*)outp)[(size_t)m * DMODEL + n] = c;
                } else if (mode == 1) {
                    const int b = m >> 11, s = m & (SEQ - 1);
                    const int h = n >> 6,  d = n & (DH - 1);
                    ((bf16*)outp)[(((size_t)(b * NHEADS + h) * SEQ) + s) * DH + d] = f2b(c);
                } else {
                    const int h = m >> 6,  d = m & (DH - 1);
                    const int b = n >> 11, s = n & (SEQ - 1);
                    const int p = s & 31;
                    const int sp = (s & ~31) | ((p & 12) << 1) | ((p & 16) >> 2) | (p & 3);
                    ((bf16*)outp)[(((size_t)(b * NHEADS + h) * DH) + d) * SEQ + sp] = f2b(c);
                }
            }
        }
    }
}

__global__ __launch_bounds__(256, 3) void gemm_one(
    const bf16* A, const bf16* B, const float* bias, void* out,
    int mode, int bias_m, float scale)
{
    gemm_body<128>(A, B, bias, out, blockIdx.x * 128, blockIdx.y * 128,
                   mode, bias_m, scale);
}

__global__ __launch_bounds__(256, 3) void gemm_fin(
    const bf16* A, const bf16* B, const float* bias, void* out)
{
    gemm_body<128>(A, B, bias, out, blockIdx.x * 128, blockIdx.y * 128, 0, 0, 1.f);
}

__global__ __launch_bounds__(256, 3) void gemm_qkv(
    const bf16* Qb, const bf16* Kb, const bf16* Vb, const bf16* Wb,
    const float* bq, const float* bk, const float* bv,
    bf16* qp, bf16* kp, bf16* vp)
{
    const int blk = blockIdx.x;
    const int z = blk >> 8, t = blk & 255;
    if (z == 0)
        gemm_body<128>(Qb, Wb,          bq, qp, (t >> 3) * 128, (t & 7) * 128, 1, 0, SCQ);
    else if (z == 1)
        gemm_body<128>(Kb, Wb + M1,     bk, kp, (t >> 3) * 128, (t & 7) * 128, 1, 0, 1.f);
    else
        gemm_body<128>(Wb + 2 * M1, Vb, bv, vp, (t >> 5) * 128, (t & 31) * 128, 2, 1, 1.f);
}

// ---------------------------------------------------------------------------
// Fused split-K attention: 512 blocks x 512 threads (8 waves). r18-verified
// (45.0us): r15 in-wave 1-deep pipeline + hoisted stage pointers + setprio.
// q,k: [B,H,S,DH] bf16 (q pre-scaled by log2e/8); vt: [B,H,DH,S] bf16,
// key-permuted (tau). out: concat [B,S,DMODEL] bf16.
// ---------------------------------------------------------------------------

// QK^T for key-group G (16 keys), both q-groups: S0 (qg=0), S1 (qg=1)
#define QKG(KTB, G, S0, S1) { \
    const short* kr_ = (KTB) + ((G) * 16 + n) * 64; \
    short8 kf0_ = *(const short8*)(kr_ + off0); \
    short8 kf1_ = *(const short8*)(kr_ + off1); \
    S0 = mfma16(kf0_, qf00, Zv); S0 = mfma16(kf1_, qf01, S0); \
    S1 = mfma16(kf0_, qf10, Zv); S1 = mfma16(kf1_, qf11, S1); }

// pack exp(SA)|exp(SB) (two adjacent key-groups) into one bf16x8
#define PKP(SA, SB, DST) { \
    union { short8 s8; unsigned u[4]; } bb_; \
    bb_.u[0] = pk2(fexp2(SA[0]), fexp2(SA[1])); \
    bb_.u[1] = pk2(fexp2(SA[2]), fexp2(SA[3])); \
    bb_.u[2] = pk2(fexp2(SB[0]), fexp2(SB[1])); \
    bb_.u[3] = pk2(fexp2(SB[2]), fexp2(SB[3])); \
    DST = bb_.s8; }

// X phase: QK^T + exp/pack for tile T -> P(tt,qg) = P00,P01,P10,P11
#define XPH(T, P00, P01, P10, P11) { \
    const short* KtB_ = Kb0 + ((T) & 1) * 4096; \
    f32x4 sa0_, sa1_, sb0_, sb1_; \
    QKG(KtB_, 0, sa0_, sa1_) \
    QKG(KtB_, 1, sb0_, sb1_) \
    PKP(sa0_, sb0_, P00) \
    PKP(sa1_, sb1_, P01) \
    QKG(KtB_, 2, sa0_, sa1_) \
    QKG(KtB_, 3, sb0_, sb1_) \
    PKP(sa0_, sb0_, P10) \
    PKP(sa1_, sb1_, P11) }

// PV for output d-group GD
#define PVG(VTB, GD, P00, P01, P10, P11) { \
    const short* vr_ = (VTB) + ((GD) * 16 + n) * 64; \
    short8 vf0_ = *(const short8*)(vr_ + off0); \
    short8 vf1_ = *(const short8*)(vr_ + off1); \
    O[GD][0] = mfma16(vf0_, P00, O[GD][0]); \
    O[GD][0] = mfma16(vf1_, P10, O[GD][0]); \
    O[GD][1] = mfma16(vf0_, P01, O[GD][1]); \
    O[GD][1] = mfma16(vf1_, P11, O[GD][1]); }

// Y phase: lacc + PV for tile T from P-tile (setprio-wrapped MFMA cluster)
#define YPH(T, P00, P01, P10, P11) { \
    const short* VtB_ = Vb0 + ((T) & 1) * 4096; \
    __builtin_amdgcn_s_setprio(1); \
    lc0 = mfma16(onesv, P00, lc0); \
    lc1 = mfma16(onesv, P01, lc1); \
    lc0 = mfma16(onesv, P10, lc0); \
    lc1 = mfma16(onesv, P11, lc1); \
    PVG(VtB_, 0, P00, P01, P10, P11) \
    PVG(VtB_, 1, P00, P01, P10, P11) \
    PVG(VtB_, 2, P00, P01, P10, P11) \
    PVG(VtB_, 3, P00, P01, P10, P11) \
    __builtin_amdgcn_s_setprio(0); }

__global__ __launch_bounds__(512, 4) void attn_fused(
    const bf16* __restrict__ q,
    const bf16* __restrict__ k,
    const bf16* __restrict__ vt,
    bf16* __restrict__ out)
{
    __shared__ short LB[32768];      // 64 KB: [half][{K0,K1,V0,V1} x 4096 shorts]

    const int tid  = threadIdx.x;
    const int wave = tid >> 6;           // 0..7
    const int half = wave >> 2;          // key-half
    const int w4   = wave & 3;
    const int lane = tid & 63;
    const int n    = lane & 15;
    const int quad = lane >> 4;

    const int blk  = blockIdx.x;         // 0..511
    const int xcd  = blk & 7;
    const int rest = blk >> 3;           // 0..63
    const int qt   = rest & 15;
    const int bh   = ((rest >> 4) << 3) | xcd;
    const int q0w  = qt * 128 + w4 * 32;
    const int kt0  = half * 16;

    const bf16* qhead = q  + (size_t)bh * SEQ * DH;
    const bf16* khead = k  + (size_t)bh * SEQ * DH;
    const bf16* vhead = vt + (size_t)bh * DH * SEQ;

    short* Kb0 = LB + half * 16384;              // [buf][4096]
    short* Vb0 = LB + half * 16384 + 8192;       // [buf][4096]

    short8 qf00, qf01, qf10, qf11;
    {
        const short* qr0 = (const short*)(qhead + (size_t)(q0w + n) * DH);
        qf00 = *(const short8*)(qr0 + quad * 8);
        qf01 = *(const short8*)(qr0 + 32 + quad * 8);
        const short* qr1 = (const short*)(qhead + (size_t)(q0w + 16 + n) * DH);
        qf10 = *(const short8*)(qr1 + quad * 8);
        qf11 = *(const short8*)(qr1 + 32 + quad * 8);
    }

    const short8 onesv = {(short)0x3F80, (short)0x3F80, (short)0x3F80, (short)0x3F80,
                          (short)0x3F80, (short)0x3F80, (short)0x3F80, (short)0x3F80};
    const f32x4 Zv = (f32x4){0.f, 0.f, 0.f, 0.f};

    f32x4 O[4][2];
#pragma unroll
    for (int gd = 0; gd < 4; ++gd)
#pragma unroll
        for (int qg = 0; qg < 2; ++qg) O[gd][qg] = Zv;
    f32x4 lc0 = Zv, lc1 = Zv;            // single l-chain per qg

    const int srow = lane >> 3;
    const int schk = (lane & 7) ^ srow;
    const int off0 = ((quad       ^ (n & 7)) * 8);
    const int off1 = (((4 + quad) ^ (n & 7)) * 8);

    // hoisted stage pointers (bytes):
    //   gk(kt,i) = khead_b + (kt*64 + w4*16 + i*8 + srow)*128 + schk*16
    //   gv(kt,i) = vhead_b + (w4*16 + i*8 + srow)*4096 + kt*128 + schk*16
    // steps: K +8192B per tile, V +128B per tile; i=1 offsets +1024B / +32768B.
    const char* gk0 = (const char*)khead +
        (size_t)(kt0 * 64 + w4 * 16 + srow) * 128 + schk * 16;
    const char* gv0 = (const char*)vhead +
        (size_t)(w4 * 16 + srow) * 4096 + kt0 * 128 + schk * 16;
    short* const ldsK = Kb0 + (w4 * 16) * 64;
    short* const ldsV = Vb0 + (w4 * 16) * 64;

    auto stageK = [&](int buf) {
        GLDS(gk0,        ldsK + buf * 4096);
        GLDS(gk0 + 1024, ldsK + buf * 4096 + 512);
        gk0 += 8192;
    };
    auto stageV = [&](int buf) {
        GLDS(gv0,         ldsV + buf * 4096);
        GLDS(gv0 + 32768, ldsV + buf * 4096 + 512);
        gv0 += 128;
    };

    short8 PA00, PA01, PA10, PA11;
    short8 PB00, PB01, PB10, PB11;

    stageK(0);                            // prologue: K(0) -> buf0

    // period 0
    __syncthreads();
    stageK(1);                            // K(1) -> buf1
    stageV(0);                            // V(0) -> buf0
    XPH(0, PA00, PA01, PA10, PA11)

#pragma unroll 1
    for (int t = 1; t < 15; t += 2) {
        // period t (odd): cur=PB, prev=PA
        __syncthreads();
        stageK((t + 1) & 1);              // K(t+1)
        stageV(t & 1);                    // V(t)
        XPH(t, PB00, PB01, PB10, PB11)
        YPH(t - 1, PA00, PA01, PA10, PA11)
        // period t+1 (even): cur=PA, prev=PB
        __syncthreads();
        stageK((t + 2) & 1);              // K(t+2)
        stageV((t + 1) & 1);              // V(t+1)
        XPH(t + 1, PA00, PA01, PA10, PA11)
        YPH(t, PB00, PB01, PB10, PB11)
    }
    // period 15: cur=PB, prev=PA (no more K to stage)
    __syncthreads();
    stageV(1);                            // V(15)
    XPH(15, PB00, PB01, PB10, PB11)
    YPH(14, PA00, PA01, PA10, PA11)
    // period 16: drain
    __syncthreads();
    YPH(15, PB00, PB01, PB10, PB11)

    // ---- intra-block split-K merge ----
    // scratch: per lane 34 floats (32 O + 2 l), stride 34 (2-way bank alias =
    // free; 8B aligned for b64). 256 lanes x 136B = 34 KB < 64 KB.
    float* scr = (float*)LB + (size_t)(w4 * 64 + lane) * 34;
    const float l0 = lc0[0];
    const float l1 = lc1[0];

    __syncthreads();                     // all tile reads done; LB reusable
    if (half == 1) {
#pragma unroll
        for (int gd = 0; gd < 4; ++gd)
#pragma unroll
            for (int qg = 0; qg < 2; ++qg) {
                *(float2*)(scr + (gd * 2 + qg) * 4)     = float2{O[gd][qg][0], O[gd][qg][1]};
                *(float2*)(scr + (gd * 2 + qg) * 4 + 2) = float2{O[gd][qg][2], O[gd][qg][3]};
            }
        *(float2*)(scr + 32) = float2{l0, l1};
    }
    __syncthreads();
    if (half == 0) {
        const float2 lo = *(const float2*)(scr + 32);
        const float inv0 = 1.0f / (l0 + lo.x);
        const float inv1 = 1.0f / (l1 + lo.y);
        const int b = bh >> 4;
        const int h = bh & (NHEADS - 1);
#pragma unroll
        for (int gd = 0; gd < 4; ++gd) {
#pragma unroll
            for (int qg = 0; qg < 2; ++qg) {
                const float iv = qg ? inv1 : inv0;
                float2 a = *(const float2*)(scr + (gd * 2 + qg) * 4);
                float2 c = *(const float2*)(scr + (gd * 2 + qg) * 4 + 2);
                const int s = q0w + qg * 16 + n;
                uint2 o;
                o.x = pk2((O[gd][qg][0] + a.x) * iv, (O[gd][qg][1] + a.y) * iv);
                o.y = pk2((O[gd][qg][2] + c.x) * iv, (O[gd][qg][3] + c.y) * iv);
                *(uint2*)(out + ((size_t)(b * SEQ + s)) * DMODEL + h * DH + gd * 16 + quad * 4) = o;
            }
        }
    }
}

#undef QKG
#undef PKP
#undef XPH
#undef PVG
#undef YPH

// ---------------------------------------------------------------------------
// Single-kernel attention — fallback path only (r9-verified).
// ---------------------------------------------------------------------------
__global__ __launch_bounds__(256) void attn_mfma(
    const bf16* __restrict__ q,
    const bf16* __restrict__ k,
    const bf16* __restrict__ vt,
    bf16* __restrict__ out)
{
    __shared__ short Kt[2][64 * 64];
    __shared__ short Vt[2][64 * 64];

    const int tid  = threadIdx.x;
    const int wave = tid >> 6;
    const int lane = tid & 63;
    const int n    = lane & 15;
    const int quad = lane >> 4;

    const int blk  = blockIdx.x;
    const int xcd  = blk & 7;
    const int rest = blk >> 3;
    const int qt   = rest & 15;
    const int bh   = ((rest >> 4) << 3) | xcd;
    const int q0w  = qt * 128 + wave * 32;

    const bf16* qhead = q  + (size_t)bh * SEQ * DH;
    const bf16* khead = k  + (size_t)bh * SEQ * DH;
    const bf16* vhead = vt + (size_t)bh * DH * SEQ;

    short8 qf[2][2];
#pragma unroll
    for (int qg = 0; qg < 2; ++qg) {
        const short* qr = (const short*)(qhead + (size_t)(q0w + qg * 16 + n) * DH);
        qf[qg][0] = *(const short8*)(qr + quad * 8);
        qf[qg][1] = *(const short8*)(qr + 32 + quad * 8);
    }

    const short8 onesv = {(short)0x3F80, (short)0x3F80, (short)0x3F80, (short)0x3F80,
                          (short)0x3F80, (short)0x3F80, (short)0x3F80, (short)0x3F80};
    const f32x4 Zv = (f32x4){0.f, 0.f, 0.f, 0.f};

    f32x4 O[4][2];
#pragma unroll
    for (int gd = 0; gd < 4; ++gd)
#pragma unroll
        for (int qg = 0; qg < 2; ++qg) O[gd][qg] = Zv;
    f32x4 lacc[2] = {Zv, Zv};

    const int srow = lane >> 3;
    const int schk = (lane & 7) ^ srow;
    const int off0 = ((quad       ^ (n & 7)) * 8);
    const int off1 = (((4 + quad) ^ (n & 7)) * 8);

    auto stage = [&](int kt, int buf) {
        const int kbase = kt * 64;
#pragma unroll
        for (int i = 0; i < 2; ++i) {
            const int r = wave * 16 + i * 8 + srow;
            const char* gk = (const char*)(khead + (size_t)(kbase + r) * DH) + schk * 16;
            const char* gv = (const char*)(vhead + (size_t)r * SEQ + kbase) + schk * 16;
            GLDS(gk, Kt[buf] + (wave * 16 + i * 8) * 64);
            GLDS(gv, Vt[buf] + (wave * 16 + i * 8) * 64);
        }
    };

    auto tile_body = [&](const short* KtB, const short* VtB) {
        f32x4 st[4][2];
#pragma unroll
        for (int g = 0; g < 4; ++g) {
            const short* kr = KtB + (g * 16 + n) * 64;
            short8 kf0 = *(const short8*)(kr + off0);
            short8 kf1 = *(const short8*)(kr + off1);
#pragma unroll
            for (int qg = 0; qg < 2; ++qg) {
                f32x4 s = mfma16(kf0, qf[qg][0], Zv);
                s = mfma16(kf1, qf[qg][1], s);
                st[g][qg] = s;
            }
        }
        short8 bP[2][2];
#pragma unroll
        for (int t = 0; t < 2; ++t) {
#pragma unroll
            for (int qg = 0; qg < 2; ++qg) {
                union { short8 s8; unsigned u[4]; } bb;
                bb.u[0] = pk2(fexp2(st[2*t][qg][0]),   fexp2(st[2*t][qg][1]));
                bb.u[1] = pk2(fexp2(st[2*t][qg][2]),   fexp2(st[2*t][qg][3]));
                bb.u[2] = pk2(fexp2(st[2*t+1][qg][0]), fexp2(st[2*t+1][qg][1]));
                bb.u[3] = pk2(fexp2(st[2*t+1][qg][2]), fexp2(st[2*t+1][qg][3]));
                bP[t][qg] = bb.s8;
                lacc[qg] = mfma16(onesv, bP[t][qg], lacc[qg]);
            }
        }
#pragma unroll
        for (int gd = 0; gd < 4; ++gd) {
            const short* vr = VtB + (gd * 16 + n) * 64;
            short8 vf0 = *(const short8*)(vr + off0);
            short8 vf1 = *(const short8*)(vr + off1);
#pragma unroll
            for (int qg = 0; qg < 2; ++qg) {
                O[gd][qg] = mfma16(vf0, bP[0][qg], O[gd][qg]);
                O[gd][qg] = mfma16(vf1, bP[1][qg], O[gd][qg]);
            }
        }
    };

    stage(0, 0);
#pragma unroll 1
    for (int kt = 0; kt < SEQ / 64; kt += 2) {
        __syncthreads();
        stage(kt + 1, 1);
        tile_body(Kt[0], Vt[0]);
        __syncthreads();
        if (kt + 2 < SEQ / 64) stage(kt + 2, 0);
        tile_body(Kt[1], Vt[1]);
    }

    const float inv0 = 1.0f / lacc[0][0];
    const float inv1 = 1.0f / lacc[1][0];
    const int b = bh >> 4;
    const int h = bh & (NHEADS - 1);
#pragma unroll
    for (int gd = 0; gd < 4; ++gd) {
#pragma unroll
        for (int qg = 0; qg < 2; ++qg) {
            const float iv = qg ? inv1 : inv0;
            const int s = q0w + qg * 16 + n;
            uint2 o;
            o.x = pk2(O[gd][qg][0] * iv, O[gd][qg][1] * iv);
            o.y = pk2(O[gd][qg][2] * iv, O[gd][qg][3] * iv);
            *(uint2*)(out + ((size_t)(b * SEQ + s)) * DMODEL + h * DH + gd * 16 + quad * 4) = o;
        }
    }
}

// ---------------------------------------------------------------------------
extern "C" void kernel_launch(void* const* d_in, const int* in_sizes, int n_in,
                              void* d_out, int out_size, void* d_ws, size_t ws_size,
                              hipStream_t stream) {
    const float* Q  = (const float*)d_in[0];
    const float* K  = (const float*)d_in[1];
    const float* V  = (const float*)d_in[2];
    const float* Wq = (const float*)d_in[3];
    const float* Wk = (const float*)d_in[4];
    const float* Wv = (const float*)d_in[5];
    const float* Wo = (const float*)d_in[6];
    const float* bq = (const float*)d_in[7];
    const float* bk = (const float*)d_in[8];
    const float* bv = (const float*)d_in[9];
    const float* bo = (const float*)d_in[10];

    // kp/vp live in d_out (16MB) as scratch; final GEMM rewrites d_out fully.
    bf16* kp = (bf16*)d_out;
    bf16* vp = kp + M4;

    dim3 bb(256);
    dim3 gqk(MROWS / 128, DMODEL / 128);   // (32,8)
    dim3 gvv(DMODEL / 128, MROWS / 128);   // (8,32)
    dim3 gfin(MROWS / 128, DMODEL / 128);  // (32,8)

    if (ws_size >= (size_t)40 * 1024 * 1024) {
        // fused: Wb 8MB | Qb 8 | Kb 8 | Vb 8 | qp 8 = 40MB; ao aliases Qb.
        bf16* Wb = (bf16*)d_ws;
        bf16* Qb = Wb + 4 * M1;
        bf16* Kb = Qb + M4;
        bf16* Vb = Kb + M4;
        bf16* qp = Vb + M4;
        bf16* ao = Qb;

        cvt_all<<<8192, bb, 0, stream>>>(Wq, Wk, Wv, Wo, Q, K, V, Wb);
        gemm_qkv<<<768, bb, 0, stream>>>(Qb, Kb, Vb, Wb, bq, bk, bv, qp, kp, vp);
        attn_fused<<<512, 512, 0, stream>>>(qp, kp, vp, ao);
        gemm_fin<<<gfin, bb, 0, stream>>>(ao, Wb + 3 * M1, bo, d_out);
    } else {
        // sequential: Wb 8 + Xb 8 + qp 8 = 24MB; ao aliases Xb
        bf16* Wb = (bf16*)d_ws;
        bf16* Xb = Wb + 4 * M1;
        bf16* qp = Xb + M4;
        bf16* ao = Xb;

        cvt_w<<<2048, bb, 0, stream>>>(Wq, Wk, Wv, Wo, Wb);
        cvt_1<<<2048, bb, 0, stream>>>(Q, Xb);
        gemm_one<<<gqk, bb, 0, stream>>>(Xb, Wb, bq, qp, 1, 0, SCQ);
        cvt_1<<<2048, bb, 0, stream>>>(K, Xb);
        gemm_one<<<gqk, bb, 0, stream>>>(Xb, Wb + M1, bk, kp, 1, 0, 1.f);
        cvt_1<<<2048, bb, 0, stream>>>(V, Xb);
        gemm_one<<<gvv, bb, 0, stream>>>(Wb + 2 * M1, Xb, bv, vp, 2, 1, 1.f);
        attn_mfma<<<512, bb, 0, stream>>>(qp, kp, vp, ao);
        gemm_fin<<<gfin, bb, 0, stream>>>(ao, Wb + 3 * M1, bo, d_out);
    }
}

// Round 8
// 209.234 us; speedup vs baseline: 1.3826x; 1.0104x over previous
//
#include <hip/hip_runtime.h>
#include <hip/hip_bf16.h>

// MultiHeadAttention  B=2, S=2048, D=1024, H=16, Dh=64  (fp32 I/O)
// Round 20:
//  - gemm_body: REVERTED to r8 single-buffer (2 barriers/step, 16KB LDS).
//    r19's double-buffer was neutral-to-negative (gemm_qkv surfaced at
//    46.1us) and introduced 3.1M LDS bank conflicts -- GLDS writes of
//    stage(t+1) colliding with ds_reads of compute(t) (r8's barrier
//    separated them). Clean experiment: if conflicts stay ~3M after revert,
//    the read pattern is the cause -> R21 swizzle.
//  - gemm_fin kept at BN=128 (r19 improvement, verified).
//  - gemm_qkv z=0/1: XCD-aware remap m0=(t&31)*128, n0=(t>>5)*128 -- the 8
//    blocks sharing an A-panel now land on ONE XCD L2 (t =~ m-idx mod 8) ->
//    panel fetched once per XCD. FETCH was 80MB vs ~30 ideal (8x A
//    over-fetch across XCDs). z=2 and gemm_fin already have this property.
//  - attn_fused: r18-verified (45.0us).

#define SEQ     2048
#define DMODEL  1024
#define NHEADS  16
#define DH      64
#define MROWS   4096
#define M1      (1024*1024)
#define M4      (4*1024*1024)
#define SCQ     0.18033688f      // log2(e)/sqrt(64)

typedef __hip_bfloat16 bf16;
typedef __attribute__((ext_vector_type(8))) short  short8;  // 8 bf16 = 4 VGPR
typedef __attribute__((ext_vector_type(4))) float  f32x4;   // MFMA C/D

__device__ __forceinline__ bf16 f2b(float x) { return __float2bfloat16(x); }
__device__ __forceinline__ f32x4 mfma16(short8 a, short8 b, f32x4 c) {
    return __builtin_amdgcn_mfma_f32_16x16x32_bf16(a, b, c, 0, 0, 0);
}
__device__ __forceinline__ unsigned pk2(float a, float b) {
    union { __hip_bfloat162 h; unsigned u; } x;
    x.h = __float22bfloat162_rn(float2{a, b});
    return x.u;
}
__device__ __forceinline__ short8 pk8(float4 a, float4 b) {
    union { short8 s; unsigned u[4]; } x;
    x.u[0] = pk2(a.x, a.y); x.u[1] = pk2(a.z, a.w);
    x.u[2] = pk2(b.x, b.y); x.u[3] = pk2(b.z, b.w);
    return x.s;
}
__device__ __forceinline__ float fexp2(float x) {
    return __builtin_amdgcn_exp2f(x);     // raw v_exp_f32
}
#define GLDS(g, l) __builtin_amdgcn_global_load_lds( \
    (const __attribute__((address_space(1))) void*)(g), \
    (__attribute__((address_space(3))) void*)(l), 16, 0, 0)

// ---------------------------------------------------------------------------
// fp32 -> bf16 conversion kernels
// ---------------------------------------------------------------------------
__global__ __launch_bounds__(256) void cvt_all(
    const float* __restrict__ Wq, const float* __restrict__ Wk,
    const float* __restrict__ Wv, const float* __restrict__ Wo,
    const float* __restrict__ Q,  const float* __restrict__ K,
    const float* __restrict__ V,  bf16* __restrict__ dst)
{
    const size_t gid = (size_t)blockIdx.x * 256 + threadIdx.x;   // 2M threads
    const size_t e0 = gid * 8;
    const float* s;
    if (e0 < (size_t)4 * M1) {
        const float* w[4] = {Wq, Wk, Wv, Wo};
        s = w[e0 >> 20] + (e0 & (M1 - 1));
    } else {
        const float* a[4] = {nullptr, Q, K, V};
        s = a[e0 >> 22] + (e0 & (M4 - 1));
    }
    float4 x = *(const float4*)s, y = *(const float4*)(s + 4);
    *(short8*)((short*)dst + e0) = pk8(x, y);
}

__global__ __launch_bounds__(256) void cvt_w(
    const float* __restrict__ W0, const float* __restrict__ W1,
    const float* __restrict__ W2, const float* __restrict__ W3,
    bf16* __restrict__ dst)
{
    const int gid = blockIdx.x * 256 + threadIdx.x;
    const int t   = gid >> 17;
    const int off = (gid & 131071) * 8;
    const float* srcs[4] = {W0, W1, W2, W3};
    const float* s = srcs[t] + off;
    float4 a = *(const float4*)s, b = *(const float4*)(s + 4);
    *(short8*)((short*)dst + (size_t)gid * 8) = pk8(a, b);
}

__global__ __launch_bounds__(256) void cvt_1(
    const float* __restrict__ X, bf16* __restrict__ D)
{
    const int gid = blockIdx.x * 256 + threadIdx.x;
    const int off = gid * 8;
    float4 a = *(const float4*)(X + off), b = *(const float4*)(X + off + 4);
    *(short8*)((short*)D + off) = pk8(a, b);
}

// ---------------------------------------------------------------------------
// bf16 MFMA GEMM body (r8-verified, BK=32 single-buffer, 2 barriers/step).
// mode: 0 fp32 flat; 1 bf16 heads [B,H,S,DH]; 2 bf16 heads-T [B,H,DH,S] with
// key-permutation tau within 32-groups (inverse realized by attn PV reads).
// ---------------------------------------------------------------------------
template <int BN>
__device__ __forceinline__ void gemm_body(
    const bf16* __restrict__ A, const bf16* __restrict__ B,
    const float* __restrict__ bias, void* __restrict__ outp,
    int m0, int n0, int mode, int bias_m, float scale)
{
    __shared__ short As[128 * 32];
    __shared__ short Bs[BN * 32];
    constexpr int NI = BN / 32;

    const int tid  = threadIdx.x;
    const int lane = tid & 63;
    const int wv   = tid >> 6;
    const int wm   = (wv >> 1) * 64;
    const int wn   = (wv & 1) * (BN / 2);
    const int fn   = lane & 15;
    const int fq   = lane >> 4;

    const int srow = lane >> 2;
    const int scol = (lane & 3) * 8;

    const short* Ag = (const short*)A;
    const short* Bg = (const short*)B;

    f32x4 acc[4][NI];
#pragma unroll
    for (int i = 0; i < 4; ++i)
#pragma unroll
        for (int j = 0; j < NI; ++j) acc[i][j] = (f32x4){0.f, 0.f, 0.f, 0.f};

    for (int k0 = 0; k0 < DMODEL; k0 += 32) {
#pragma unroll
        for (int i = 0; i < 2; ++i) {
            const int rr = wv * 32 + i * 16;
            const short* ga = Ag + (size_t)(m0 + rr + srow) * DMODEL + k0 + scol;
            GLDS(ga, As + rr * 32);
        }
#pragma unroll
        for (int i = 0; i < BN / 64; ++i) {
            const int rr = wv * (BN / 4) + i * 16;
            const short* gb = Bg + (size_t)(n0 + rr + srow) * DMODEL + k0 + scol;
            GLDS(gb, Bs + rr * 32);
        }
        __syncthreads();

        short8 af[4], bfr[NI];
#pragma unroll
        for (int im = 0; im < 4; ++im)
            af[im] = *(const short8*)(As + (wm + im * 16 + fn) * 32 + fq * 8);
#pragma unroll
        for (int in = 0; in < NI; ++in)
            bfr[in] = *(const short8*)(Bs + (wn + in * 16 + fn) * 32 + fq * 8);
#pragma unroll
        for (int im = 0; im < 4; ++im)
#pragma unroll
            for (int in = 0; in < NI; ++in)
                acc[im][in] = mfma16(af[im], bfr[in], acc[im][in]);
        __syncthreads();
    }

#pragma unroll
    for (int im = 0; im < 4; ++im) {
#pragma unroll
        for (int in = 0; in < NI; ++in) {
#pragma unroll
            for (int r = 0; r < 4; ++r) {
                const int m = m0 + wm + im * 16 + fq * 4 + r;
                const int n = n0 + wn + in * 16 + fn;
                const float c = (acc[im][in][r] + (bias_m ? bias[m] : bias[n])) * scale;
                if (mode == 0) {
                    ((float*)outp)[(size_t)m * DMODEL + n] = c;
                } else if (mode == 1) {
                    const int b = m >> 11, s = m & (SEQ - 1);
                    const int h = n >> 6,  d = n & (DH - 1);
                    ((bf16*)outp)[(((size_t)(b * NHEADS + h) * SEQ) + s) * DH + d] = f2b(c);
                } else {
                    const int h = m >> 6,  d = m & (DH - 1);
                    const int b = n >> 11, s = n & (SEQ - 1);
                    const int p = s & 31;
                    const int sp = (s & ~31) | ((p & 12) << 1) | ((p & 16) >> 2) | (p & 3);
                    ((bf16*)outp)[(((size_t)(b * NHEADS + h) * DH) + d) * SEQ + sp] = f2b(c);
                }
            }
        }
    }
}

__global__ __launch_bounds__(256, 3) void gemm_one(
    const bf16* A, const bf16* B, const float* bias, void* out,
    int mode, int bias_m, float scale)
{
    gemm_body<128>(A, B, bias, out, blockIdx.x * 128, blockIdx.y * 128,
                   mode, bias_m, scale);
}

__global__ __launch_bounds__(256, 3) void gemm_fin(
    const bf16* A, const bf16* B, const float* bias, void* out)
{
    gemm_body<128>(A, B, bias, out, blockIdx.x * 128, blockIdx.y * 128, 0, 0, 1.f);
}

__global__ __launch_bounds__(256, 3) void gemm_qkv(
    const bf16* Qb, const bf16* Kb, const bf16* Vb, const bf16* Wb,
    const float* bq, const float* bk, const float* bv,
    bf16* qp, bf16* kp, bf16* vp)
{
    const int blk = blockIdx.x;
    const int z = blk >> 8, t = blk & 255;
    // z=0/1: m0=(t&31), n0=(t>>5): same-A-panel blocks (n varies) share
    // t mod 8 -> same XCD L2 -> A-panel fetched once per XCD.
    if (z == 0)
        gemm_body<128>(Qb, Wb,          bq, qp, (t & 31) * 128, (t >> 5) * 128, 1, 0, SCQ);
    else if (z == 1)
        gemm_body<128>(Kb, Wb + M1,     bk, kp, (t & 31) * 128, (t >> 5) * 128, 1, 0, 1.f);
    else
        gemm_body<128>(Wb + 2 * M1, Vb, bv, vp, (t >> 5) * 128, (t & 31) * 128, 2, 1, 1.f);
}

// ---------------------------------------------------------------------------
// Fused split-K attention: 512 blocks x 512 threads (8 waves). r18-verified
// (45.0us): r15 in-wave 1-deep pipeline + hoisted stage pointers + setprio.
// q,k: [B,H,S,DH] bf16 (q pre-scaled by log2e/8); vt: [B,H,DH,S] bf16,
// key-permuted (tau). out: concat [B,S,DMODEL] bf16.
// ---------------------------------------------------------------------------

// QK^T for key-group G (16 keys), both q-groups: S0 (qg=0), S1 (qg=1)
#define QKG(KTB, G, S0, S1) { \
    const short* kr_ = (KTB) + ((G) * 16 + n) * 64; \
    short8 kf0_ = *(const short8*)(kr_ + off0); \
    short8 kf1_ = *(const short8*)(kr_ + off1); \
    S0 = mfma16(kf0_, qf00, Zv); S0 = mfma16(kf1_, qf01, S0); \
    S1 = mfma16(kf0_, qf10, Zv); S1 = mfma16(kf1_, qf11, S1); }

// pack exp(SA)|exp(SB) (two adjacent key-groups) into one bf16x8
#define PKP(SA, SB, DST) { \
    union { short8 s8; unsigned u[4]; } bb_; \
    bb_.u[0] = pk2(fexp2(SA[0]), fexp2(SA[1])); \
    bb_.u[1] = pk2(fexp2(SA[2]), fexp2(SA[3])); \
    bb_.u[2] = pk2(fexp2(SB[0]), fexp2(SB[1])); \
    bb_.u[3] = pk2(fexp2(SB[2]), fexp2(SB[3])); \
    DST = bb_.s8; }

// X phase: QK^T + exp/pack for tile T -> P(tt,qg) = P00,P01,P10,P11
#define XPH(T, P00, P01, P10, P11) { \
    const short* KtB_ = Kb0 + ((T) & 1) * 4096; \
    f32x4 sa0_, sa1_, sb0_, sb1_; \
    QKG(KtB_, 0, sa0_, sa1_) \
    QKG(KtB_, 1, sb0_, sb1_) \
    PKP(sa0_, sb0_, P00) \
    PKP(sa1_, sb1_, P01) \
    QKG(KtB_, 2, sa0_, sa1_) \
    QKG(KtB_, 3, sb0_, sb1_) \
    PKP(sa0_, sb0_, P10) \
    PKP(sa1_, sb1_, P11) }

// PV for output d-group GD
#define PVG(VTB, GD, P00, P01, P10, P11) { \
    const short* vr_ = (VTB) + ((GD) * 16 + n) * 64; \
    short8 vf0_ = *(const short8*)(vr_ + off0); \
    short8 vf1_ = *(const short8*)(vr_ + off1); \
    O[GD][0] = mfma16(vf0_, P00, O[GD][0]); \
    O[GD][0] = mfma16(vf1_, P10, O[GD][0]); \
    O[GD][1] = mfma16(vf0_, P01, O[GD][1]); \
    O[GD][1] = mfma16(vf1_, P11, O[GD][1]); }

// Y phase: lacc + PV for tile T from P-tile (setprio-wrapped MFMA cluster)
#define YPH(T, P00, P01, P10, P11) { \
    const short* VtB_ = Vb0 + ((T) & 1) * 4096; \
    __builtin_amdgcn_s_setprio(1); \
    lc0 = mfma16(onesv, P00, lc0); \
    lc1 = mfma16(onesv, P01, lc1); \
    lc0 = mfma16(onesv, P10, lc0); \
    lc1 = mfma16(onesv, P11, lc1); \
    PVG(VtB_, 0, P00, P01, P10, P11) \
    PVG(VtB_, 1, P00, P01, P10, P11) \
    PVG(VtB_, 2, P00, P01, P10, P11) \
    PVG(VtB_, 3, P00, P01, P10, P11) \
    __builtin_amdgcn_s_setprio(0); }

__global__ __launch_bounds__(512, 4) void attn_fused(
    const bf16* __restrict__ q,
    const bf16* __restrict__ k,
    const bf16* __restrict__ vt,
    bf16* __restrict__ out)
{
    __shared__ short LB[32768];      // 64 KB: [half][{K0,K1,V0,V1} x 4096 shorts]

    const int tid  = threadIdx.x;
    const int wave = tid >> 6;           // 0..7
    const int half = wave >> 2;          // key-half
    const int w4   = wave & 3;
    const int lane = tid & 63;
    const int n    = lane & 15;
    const int quad = lane >> 4;

    const int blk  = blockIdx.x;         // 0..511
    const int xcd  = blk & 7;
    const int rest = blk >> 3;           // 0..63
    const int qt   = rest & 15;
    const int bh   = ((rest >> 4) << 3) | xcd;
    const int q0w  = qt * 128 + w4 * 32;
    const int kt0  = half * 16;

    const bf16* qhead = q  + (size_t)bh * SEQ * DH;
    const bf16* khead = k  + (size_t)bh * SEQ * DH;
    const bf16* vhead = vt + (size_t)bh * DH * SEQ;

    short* Kb0 = LB + half * 16384;              // [buf][4096]
    short* Vb0 = LB + half * 16384 + 8192;       // [buf][4096]

    short8 qf00, qf01, qf10, qf11;
    {
        const short* qr0 = (const short*)(qhead + (size_t)(q0w + n) * DH);
        qf00 = *(const short8*)(qr0 + quad * 8);
        qf01 = *(const short8*)(qr0 + 32 + quad * 8);
        const short* qr1 = (const short*)(qhead + (size_t)(q0w + 16 + n) * DH);
        qf10 = *(const short8*)(qr1 + quad * 8);
        qf11 = *(const short8*)(qr1 + 32 + quad * 8);
    }

    const short8 onesv = {(short)0x3F80, (short)0x3F80, (short)0x3F80, (short)0x3F80,
                          (short)0x3F80, (short)0x3F80, (short)0x3F80, (short)0x3F80};
    const f32x4 Zv = (f32x4){0.f, 0.f, 0.f, 0.f};

    f32x4 O[4][2];
#pragma unroll
    for (int gd = 0; gd < 4; ++gd)
#pragma unroll
        for (int qg = 0; qg < 2; ++qg) O[gd][qg] = Zv;
    f32x4 lc0 = Zv, lc1 = Zv;            // single l-chain per qg

    const int srow = lane >> 3;
    const int schk = (lane & 7) ^ srow;
    const int off0 = ((quad       ^ (n & 7)) * 8);
    const int off1 = (((4 + quad) ^ (n & 7)) * 8);

    // hoisted stage pointers (bytes):
    //   gk(kt,i) = khead_b + (kt*64 + w4*16 + i*8 + srow)*128 + schk*16
    //   gv(kt,i) = vhead_b + (w4*16 + i*8 + srow)*4096 + kt*128 + schk*16
    // steps: K +8192B per tile, V +128B per tile; i=1 offsets +1024B / +32768B.
    const char* gk0 = (const char*)khead +
        (size_t)(kt0 * 64 + w4 * 16 + srow) * 128 + schk * 16;
    const char* gv0 = (const char*)vhead +
        (size_t)(w4 * 16 + srow) * 4096 + kt0 * 128 + schk * 16;
    short* const ldsK = Kb0 + (w4 * 16) * 64;
    short* const ldsV = Vb0 + (w4 * 16) * 64;

    auto stageK = [&](int buf) {
        GLDS(gk0,        ldsK + buf * 4096);
        GLDS(gk0 + 1024, ldsK + buf * 4096 + 512);
        gk0 += 8192;
    };
    auto stageV = [&](int buf) {
        GLDS(gv0,         ldsV + buf * 4096);
        GLDS(gv0 + 32768, ldsV + buf * 4096 + 512);
        gv0 += 128;
    };

    short8 PA00, PA01, PA10, PA11;
    short8 PB00, PB01, PB10, PB11;

    stageK(0);                            // prologue: K(0) -> buf0

    // period 0
    __syncthreads();
    stageK(1);                            // K(1) -> buf1
    stageV(0);                            // V(0) -> buf0
    XPH(0, PA00, PA01, PA10, PA11)

#pragma unroll 1
    for (int t = 1; t < 15; t += 2) {
        // period t (odd): cur=PB, prev=PA
        __syncthreads();
        stageK((t + 1) & 1);              // K(t+1)
        stageV(t & 1);                    // V(t)
        XPH(t, PB00, PB01, PB10, PB11)
        YPH(t - 1, PA00, PA01, PA10, PA11)
        // period t+1 (even): cur=PA, prev=PB
        __syncthreads();
        stageK((t + 2) & 1);              // K(t+2)
        stageV((t + 1) & 1);              // V(t+1)
        XPH(t + 1, PA00, PA01, PA10, PA11)
        YPH(t, PB00, PB01, PB10, PB11)
    }
    // period 15: cur=PB, prev=PA (no more K to stage)
    __syncthreads();
    stageV(1);                            // V(15)
    XPH(15, PB00, PB01, PB10, PB11)
    YPH(14, PA00, PA01, PA10, PA11)
    // period 16: drain
    __syncthreads();
    YPH(15, PB00, PB01, PB10, PB11)

    // ---- intra-block split-K merge ----
    // scratch: per lane 34 floats (32 O + 2 l), stride 34 (2-way bank alias =
    // free; 8B aligned for b64). 256 lanes x 136B = 34 KB < 64 KB.
    float* scr = (float*)LB + (size_t)(w4 * 64 + lane) * 34;
    const float l0 = lc0[0];
    const float l1 = lc1[0];

    __syncthreads();                     // all tile reads done; LB reusable
    if (half == 1) {
#pragma unroll
        for (int gd = 0; gd < 4; ++gd)
#pragma unroll
            for (int qg = 0; qg < 2; ++qg) {
                *(float2*)(scr + (gd * 2 + qg) * 4)     = float2{O[gd][qg][0], O[gd][qg][1]};
                *(float2*)(scr + (gd * 2 + qg) * 4 + 2) = float2{O[gd][qg][2], O[gd][qg][3]};
            }
        *(float2*)(scr + 32) = float2{l0, l1};
    }
    __syncthreads();
    if (half == 0) {
        const float2 lo = *(const float2*)(scr + 32);
        const float inv0 = 1.0f / (l0 + lo.x);
        const float inv1 = 1.0f / (l1 + lo.y);
        const int b = bh >> 4;
        const int h = bh & (NHEADS - 1);
#pragma unroll
        for (int gd = 0; gd < 4; ++gd) {
#pragma unroll
            for (int qg = 0; qg < 2; ++qg) {
                const float iv = qg ? inv1 : inv0;
                float2 a = *(const float2*)(scr + (gd * 2 + qg) * 4);
                float2 c = *(const float2*)(scr + (gd * 2 + qg) * 4 + 2);
                const int s = q0w + qg * 16 + n;
                uint2 o;
                o.x = pk2((O[gd][qg][0] + a.x) * iv, (O[gd][qg][1] + a.y) * iv);
                o.y = pk2((O[gd][qg][2] + c.x) * iv, (O[gd][qg][3] + c.y) * iv);
                *(uint2*)(out + ((size_t)(b * SEQ + s)) * DMODEL + h * DH + gd * 16 + quad * 4) = o;
            }
        }
    }
}

#undef QKG
#undef PKP
#undef XPH
#undef PVG
#undef YPH

// ---------------------------------------------------------------------------
// Single-kernel attention — fallback path only (r9-verified).
// ---------------------------------------------------------------------------
__global__ __launch_bounds__(256) void attn_mfma(
    const bf16* __restrict__ q,
    const bf16* __restrict__ k,
    const bf16* __restrict__ vt,
    bf16* __restrict__ out)
{
    __shared__ short Kt[2][64 * 64];
    __shared__ short Vt[2][64 * 64];

    const int tid  = threadIdx.x;
    const int wave = tid >> 6;
    const int lane = tid & 63;
    const int n    = lane & 15;
    const int quad = lane >> 4;

    const int blk  = blockIdx.x;
    const int xcd  = blk & 7;
    const int rest = blk >> 3;
    const int qt   = rest & 15;
    const int bh   = ((rest >> 4) << 3) | xcd;
    const int q0w  = qt * 128 + wave * 32;

    const bf16* qhead = q  + (size_t)bh * SEQ * DH;
    const bf16* khead = k  + (size_t)bh * SEQ * DH;
    const bf16* vhead = vt + (size_t)bh * DH * SEQ;

    short8 qf[2][2];
#pragma unroll
    for (int qg = 0; qg < 2; ++qg) {
        const short* qr = (const short*)(qhead + (size_t)(q0w + qg * 16 + n) * DH);
        qf[qg][0] = *(const short8*)(qr + quad * 8);
        qf[qg][1] = *(const short8*)(qr + 32 + quad * 8);
    }

    const short8 onesv = {(short)0x3F80, (short)0x3F80, (short)0x3F80, (short)0x3F80,
                          (short)0x3F80, (short)0x3F80, (short)0x3F80, (short)0x3F80};
    const f32x4 Zv = (f32x4){0.f, 0.f, 0.f, 0.f};

    f32x4 O[4][2];
#pragma unroll
    for (int gd = 0; gd < 4; ++gd)
#pragma unroll
        for (int qg = 0; qg < 2; ++qg) O[gd][qg] = Zv;
    f32x4 lacc[2] = {Zv, Zv};

    const int srow = lane >> 3;
    const int schk = (lane & 7) ^ srow;
    const int off0 = ((quad       ^ (n & 7)) * 8);
    const int off1 = (((4 + quad) ^ (n & 7)) * 8);

    auto stage = [&](int kt, int buf) {
        const int kbase = kt * 64;
#pragma unroll
        for (int i = 0; i < 2; ++i) {
            const int r = wave * 16 + i * 8 + srow;
            const char* gk = (const char*)(khead + (size_t)(kbase + r) * DH) + schk * 16;
            const char* gv = (const char*)(vhead + (size_t)r * SEQ + kbase) + schk * 16;
            GLDS(gk, Kt[buf] + (wave * 16 + i * 8) * 64);
            GLDS(gv, Vt[buf] + (wave * 16 + i * 8) * 64);
        }
    };

    auto tile_body = [&](const short* KtB, const short* VtB) {
        f32x4 st[4][2];
#pragma unroll
        for (int g = 0; g < 4; ++g) {
            const short* kr = KtB + (g * 16 + n) * 64;
            short8 kf0 = *(const short8*)(kr + off0);
            short8 kf1 = *(const short8*)(kr + off1);
#pragma unroll
            for (int qg = 0; qg < 2; ++qg) {
                f32x4 s = mfma16(kf0, qf[qg][0], Zv);
                s = mfma16(kf1, qf[qg][1], s);
                st[g][qg] = s;
            }
        }
        short8 bP[2][2];
#pragma unroll
        for (int t = 0; t < 2; ++t) {
#pragma unroll
            for (int qg = 0; qg < 2; ++qg) {
                union { short8 s8; unsigned u[4]; } bb;
                bb.u[0] = pk2(fexp2(st[2*t][qg][0]),   fexp2(st[2*t][qg][1]));
                bb.u[1] = pk2(fexp2(st[2*t][qg][2]),   fexp2(st[2*t][qg][3]));
                bb.u[2] = pk2(fexp2(st[2*t+1][qg][0]), fexp2(st[2*t+1][qg][1]));
                bb.u[3] = pk2(fexp2(st[2*t+1][qg][2]), fexp2(st[2*t+1][qg][3]));
                bP[t][qg] = bb.s8;
                lacc[qg] = mfma16(onesv, bP[t][qg], lacc[qg]);
            }
        }
#pragma unroll
        for (int gd = 0; gd < 4; ++gd) {
            const short* vr = VtB + (gd * 16 + n) * 64;
            short8 vf0 = *(const short8*)(vr + off0);
            short8 vf1 = *(const short8*)(vr + off1);
#pragma unroll
            for (int qg = 0; qg < 2; ++qg) {
                O[gd][qg] = mfma16(vf0, bP[0][qg], O[gd][qg]);
                O[gd][qg] = mfma16(vf1, bP[1][qg], O[gd][qg]);
            }
        }
    };

    stage(0, 0);
#pragma unroll 1
    for (int kt = 0; kt < SEQ / 64; kt += 2) {
        __syncthreads();
        stage(kt + 1, 1);
        tile_body(Kt[0], Vt[0]);
        __syncthreads();
        if (kt + 2 < SEQ / 64) stage(kt + 2, 0);
        tile_body(Kt[1], Vt[1]);
    }

    const float inv0 = 1.0f / lacc[0][0];
    const float inv1 = 1.0f / lacc[1][0];
    const int b = bh >> 4;
    const int h = bh & (NHEADS - 1);
#pragma unroll
    for (int gd = 0; gd < 4; ++gd) {
#pragma unroll
        for (int qg = 0; qg < 2; ++qg) {
            const float iv = qg ? inv1 : inv0;
            const int s = q0w + qg * 16 + n;
            uint2 o;
            o.x = pk2(O[gd][qg][0] * iv, O[gd][qg][1] * iv);
            o.y = pk2(O[gd][qg][2] * iv, O[gd][qg][3] * iv);
            *(uint2*)(out + ((size_t)(b * SEQ + s)) * DMODEL + h * DH + gd * 16 + quad * 4) = o;
        }
    }
}

// ---------------------------------------------------------------------------
extern "C" void kernel_launch(void* const* d_in, const int* in_sizes, int n_in,
                              void* d_out, int out_size, void* d_ws, size_t ws_size,
                              hipStream_t stream) {
    const float* Q  = (const float*)d_in[0];
    const float* K  = (const float*)d_in[1];
    const float* V  = (const float*)d_in[2];
    const float* Wq = (const float*)d_in[3];
    const float* Wk = (const float*)d_in[4];
    const float* Wv = (const float*)d_in[5];
    const float* Wo = (const float*)d_in[6];
    const float* bq = (const float*)d_in[7];
    const float* bk = (const float*)d_in[8];
    const float* bv = (const float*)d_in[9];
    const float* bo = (const float*)d_in[10];

    // kp/vp live in d_out (16MB) as scratch; final GEMM rewrites d_out fully.
    bf16* kp = (bf16*)d_out;
    bf16* vp = kp + M4;

    dim3 bb(256);
    dim3 gqk(MROWS / 128, DMODEL / 128);   // (32,8)
    dim3 gvv(DMODEL / 128, MROWS / 128);   // (8,32)
    dim3 gfin(MROWS / 128, DMODEL / 128);  // (32,8)

    if (ws_size >= (size_t)40 * 1024 * 1024) {
        // fused: Wb 8MB | Qb 8 | Kb 8 | Vb 8 | qp 8 = 40MB; ao aliases Qb.
        bf16* Wb = (bf16*)d_ws;
        bf16* Qb = Wb + 4 * M1;
        bf16* Kb = Qb + M4;
        bf16* Vb = Kb + M4;
        bf16* qp = Vb + M4;
        bf16* ao = Qb;

        cvt_all<<<8192, bb, 0, stream>>>(Wq, Wk, Wv, Wo, Q, K, V, Wb);
        gemm_qkv<<<768, bb, 0, stream>>>(Qb, Kb, Vb, Wb, bq, bk, bv, qp, kp, vp);
        attn_fused<<<512, 512, 0, stream>>>(qp, kp, vp, ao);
        gemm_fin<<<gfin, bb, 0, stream>>>(ao, Wb + 3 * M1, bo, d_out);
    } else {
        // sequential: Wb 8 + Xb 8 + qp 8 = 24MB; ao aliases Xb
        bf16* Wb = (bf16*)d_ws;
        bf16* Xb = Wb + 4 * M1;
        bf16* qp = Xb + M4;
        bf16* ao = Xb;

        cvt_w<<<2048, bb, 0, stream>>>(Wq, Wk, Wv, Wo, Wb);
        cvt_1<<<2048, bb, 0, stream>>>(Q, Xb);
        gemm_one<<<gqk, bb, 0, stream>>>(Xb, Wb, bq, qp, 1, 0, SCQ);
        cvt_1<<<2048, bb, 0, stream>>>(K, Xb);
        gemm_one<<<gqk, bb, 0, stream>>>(Xb, Wb + M1, bk, kp, 1, 0, 1.f);
        cvt_1<<<2048, bb, 0, stream>>>(V, Xb);
        gemm_one<<<gvv, bb, 0, stream>>>(Wb + 2 * M1, Xb, bv, vp, 2, 1, 1.f);
        attn_mfma<<<512, bb, 0, stream>>>(qp, kp, vp, ao);
        gemm_fin<<<gfin, bb, 0, stream>>>(ao, Wb + 3 * M1, bo, d_out);
    }
}